// Round 5
// baseline (244.186 us; speedup 1.0000x reference)
//
#include <hip/hip_runtime.h>
#include <hip/hip_bf16.h>

// Problem constants (B=1)
#define T_ 8
#define H_ 64
#define W_ 64
#define C_ 64
#define HW_ (H_ * W_)          // 4096
#define THW_ (T_ * H_ * W_)    // 32768
#define KTAPS 27
#define KDIM (C_ * KTAPS)      // 1728
#define NOFF 54
#define OSTR 56                // LDS offsets panel stride (floats)

typedef __bf16 bf16x8 __attribute__((ext_vector_type(8)));
typedef float floatx4 __attribute__((ext_vector_type(4)));

// ---------------------------------------------------------------------------
// prep + to_cl merged: one launch, disjoint outputs.
//  ws[tap*4096 + g16*1024 + s*512 + lane*8 + j]
//    = W[co = g16*16 + (lane&15)][cin = s*32 + (lane>>4)*8 + j][tap]
// ---------------------------------------------------------------------------
__global__ __launch_bounds__(256) void prep_tocl_kernel(
    const float* __restrict__ x, __hip_bfloat16* __restrict__ xcl,
    const float* __restrict__ w1, const float* __restrict__ woff,
    const float* __restrict__ wd, const float* __restrict__ wr,
    __hip_bfloat16* __restrict__ w1s, __hip_bfloat16* __restrict__ woffs,
    __hip_bfloat16* __restrict__ wds, __hip_bfloat16* __restrict__ wrs) {
    __shared__ float tile[64][65];
    const int tid = threadIdx.x;

    {
        int i = blockIdx.x * 256 + tid;
        if (i < C_ * KDIM) {
            int j = i & 7, lane = (i >> 3) & 63, s = (i >> 9) & 1, g16 = (i >> 10) & 3, tap = i >> 12;
            int co = g16 * 16 + (lane & 15);
            int cin = s * 32 + (lane >> 4) * 8 + j;
            int src = (co * C_ + cin) * KTAPS + tap;
            w1s[i] = __float2bfloat16(w1[src]);
            woffs[i] = (co < NOFF) ? __float2bfloat16(woff[src]) : __float2bfloat16(0.f);
            wds[i] = __float2bfloat16(wd[src]);
        }
        if (i < C_ * C_) {
            int j = i & 7, lane = (i >> 3) & 63, s = (i >> 9) & 1, g16 = i >> 10;
            int co = g16 * 16 + (lane & 15);
            int cin = s * 32 + (lane >> 4) * 8 + j;
            wrs[i] = __float2bfloat16(wr[co * C_ + cin]);
        }
    }

    const int pos0 = blockIdx.x * 64;
    for (int i = tid; i < 4096; i += 256) {
        int ch = i >> 6, p = i & 63;
        tile[ch][p] = x[ch * THW_ + pos0 + p];
    }
    __syncthreads();
    for (int i = tid; i < 4096; i += 256) {
        int p = i >> 6, ch = i & 63;
        xcl[(pos0 + p) * C_ + ch] = __float2bfloat16(tile[ch][p]);
    }
}

// ---------------------------------------------------------------------------
// BARRIER-FREE per-wave streaming MFMA 3x3x3 conv (conv1) — EXACT R12 form.
// ---------------------------------------------------------------------------
__global__ __launch_bounds__(256) void conv_stream_kernel(
    const __hip_bfloat16* __restrict__ in_cl,
    const __hip_bfloat16* __restrict__ wTs,   // swizzled (27*4096)
    const float* __restrict__ bias,
    __hip_bfloat16* __restrict__ out_cl_b16) {
    __shared__ __hip_bfloat16 ts[32 * 72];    // 4608B bounce

    const int tid = threadIdx.x;
    const int wv = tid >> 6;
    const int lane = tid & 63;
    const int l15 = lane & 15;
    const int quad = lane >> 4;
    const int wh = blockIdx.x & 1;
    const int h = (blockIdx.x >> 1) & 63;
    const int t = blockIdx.x >> 7;
    const int w0 = wh * 32;
    const int pg = wv >> 1;
    const int chf = wv & 1;
    const int wpos = w0 + pg * 16 + l15;
    const int posbase = t * HW_ + h * W_;

    floatx4 acc0 = (floatx4){0.f, 0.f, 0.f, 0.f};
    floatx4 acc1 = (floatx4){0.f, 0.f, 0.f, 0.f};
    const bf16x8 z = {};
    const __hip_bfloat16* wb = wTs + chf * 2048 + lane * 8;

    const int ktlo = (t == 0) ? 1 : 0;
    const int kthi = (t == T_ - 1) ? 2 : 3;

    for (int kt = ktlo; kt < kthi; ++kt) {
        const int t_in = t - 1 + kt;
#pragma unroll 1
        for (int kh = 0; kh < 3; ++kh) {
            const int h_in = h - 1 + kh;
            if ((unsigned)h_in >= H_) continue;
            const int rowbase = t_in * HW_ + h_in * W_;
#pragma unroll
            for (int kw = 0; kw < 3; ++kw) {
                const int tap = kt * 9 + kh * 3 + kw;
                const int w_in = wpos - 1 + kw;
                const bool v = (unsigned)w_in < W_;
                const int wc = v ? w_in : 0;
                const __hip_bfloat16* ap = in_cl + (rowbase + wc) * C_ + quad * 8;
                bf16x8 a0 = *(const bf16x8*)(ap);
                bf16x8 a1 = *(const bf16x8*)(ap + 32);
                a0 = v ? a0 : z;
                a1 = v ? a1 : z;
                const __hip_bfloat16* bp = wb + tap * 4096;
                const bf16x8 b00 = *(const bf16x8*)(bp);
                const bf16x8 b01 = *(const bf16x8*)(bp + 512);
                const bf16x8 b10 = *(const bf16x8*)(bp + 1024);
                const bf16x8 b11 = *(const bf16x8*)(bp + 1536);
                acc0 = __builtin_amdgcn_mfma_f32_16x16x32_bf16(a0, b00, acc0, 0, 0, 0);
                acc0 = __builtin_amdgcn_mfma_f32_16x16x32_bf16(a1, b01, acc0, 0, 0, 0);
                acc1 = __builtin_amdgcn_mfma_f32_16x16x32_bf16(a0, b10, acc1, 0, 0, 0);
                acc1 = __builtin_amdgcn_mfma_f32_16x16x32_bf16(a1, b11, acc1, 0, 0, 0);
            }
        }
    }

    const int n0 = chf * 32 + l15;
    const float bv0 = bias[n0], bv1 = bias[n0 + 16];
#pragma unroll
    for (int r = 0; r < 4; ++r) {
        const int p = pg * 16 + quad * 4 + r;
        float v0 = acc0[r] + bv0;
        v0 = (v0 >= 0.f) ? v0 : 0.01f * v0;
        float v1 = acc1[r] + bv1;
        v1 = (v1 >= 0.f) ? v1 : 0.01f * v1;
        ts[p * 72 + n0] = __float2bfloat16(v0);
        ts[p * 72 + n0 + 16] = __float2bfloat16(v1);
    }
    __syncthreads();
    {
        const int p = tid >> 3, ck = tid & 7;
        const uint4 v4 = *(const uint4*)&ts[p * 72 + ck * 8];
        *(uint4*)&out_cl_b16[(posbase + w0 + p) * C_ + ck * 8] = v4;
    }
}

// ---------------------------------------------------------------------------
// FUSED offsets-conv + deformable conv + 1x1 residual (R22).
//  Phase 1: unchanged cooperative offsets conv -> LDS offs (one barrier).
//  Phase 2: WAVE-AUTONOMOUS deform. Wave wv owns (pos-tile pt=wv&1 -> 16
//   positions, out-channel half chh=wv>>1 -> 32 channels). Each lane
//   gathers+blends EXACTLY its MFMA A-fragment: position l15, channels
//   quad*8 (lo frag) and 32+quad*8 (hi frag) — the same A layout that the
//   proven conv_stream kernel loads directly. So there is NO LDS panel, NO
//   transpose, and NO barrier anywhere in the 27-tap loop: waves run free,
//   and the blend VALU (the dominant real work) can saturate across waves.
//   Out-channel split (not K-split): each wave owns its outputs outright,
//   no cross-wave reduction. 4 MFMA/wave/tap (2 outch groups x 2 K-halves,
//   accumulated into the same acc[g] -> full K=64 per output).
// ---------------------------------------------------------------------------
struct G2 {
    bf16x8 a[4];          // 4 bilinear corners, channels quad*8 .. +7
    bf16x8 b[4];          // 4 corners, channels 32+quad*8 .. +7
    float w00, w01, w10, w11;
};

__global__ __launch_bounds__(256) void deform_fused_kernel(
    const __hip_bfloat16* __restrict__ y1b,
    const __hip_bfloat16* __restrict__ woffs, const float* __restrict__ boff,
    const __hip_bfloat16* __restrict__ wds, const float* __restrict__ bd,
    const __hip_bfloat16* __restrict__ xclb, const __hip_bfloat16* __restrict__ wrs,
    const float* __restrict__ br, float* __restrict__ out) {
    __shared__ float offs[32 * OSTR];        // 7168 B — ONLY LDS in this kernel

    const int tid = threadIdx.x;
    const int wv = tid >> 6;
    const int lane = tid & 63;
    const int l15 = lane & 15;
    const int quad = lane >> 4;
    const int wh = blockIdx.x & 1;
    const int h = (blockIdx.x >> 1) & 63;
    const int t = blockIdx.x >> 7;
    const int w0 = wh * 32;
    const int posbase = t * HW_ + h * W_ + w0;

    // ================= Phase 1: offsets conv -> LDS (R12, unchanged) ======
    {
        const int pg = wv >> 1;
        const int chf = wv & 1;
        const int wpos = w0 + pg * 16 + l15;
        floatx4 oa0 = (floatx4){0.f, 0.f, 0.f, 0.f};
        floatx4 oa1 = (floatx4){0.f, 0.f, 0.f, 0.f};
        const bf16x8 z = {};
        const __hip_bfloat16* wb = woffs + chf * 2048 + lane * 8;
        const int ktlo = (t == 0) ? 1 : 0;
        const int kthi = (t == T_ - 1) ? 2 : 3;

        for (int kt = ktlo; kt < kthi; ++kt) {
            const int t_in = t - 1 + kt;
#pragma unroll 1
            for (int kh = 0; kh < 3; ++kh) {
                const int h_in = h - 1 + kh;
                if ((unsigned)h_in >= H_) continue;
                const int rowbase = t_in * HW_ + h_in * W_;
#pragma unroll
                for (int kw = 0; kw < 3; ++kw) {
                    const int tap = kt * 9 + kh * 3 + kw;
                    const int w_in = wpos - 1 + kw;
                    const bool v = (unsigned)w_in < W_;
                    const int wc = v ? w_in : 0;
                    const __hip_bfloat16* ap = y1b + (rowbase + wc) * C_ + quad * 8;
                    bf16x8 a0 = *(const bf16x8*)(ap);
                    bf16x8 a1 = *(const bf16x8*)(ap + 32);
                    a0 = v ? a0 : z;
                    a1 = v ? a1 : z;
                    const __hip_bfloat16* bp = wb + tap * 4096;
                    const bf16x8 b00 = *(const bf16x8*)(bp);
                    const bf16x8 b01 = *(const bf16x8*)(bp + 512);
                    const bf16x8 b10 = *(const bf16x8*)(bp + 1024);
                    const bf16x8 b11 = *(const bf16x8*)(bp + 1536);
                    oa0 = __builtin_amdgcn_mfma_f32_16x16x32_bf16(a0, b00, oa0, 0, 0, 0);
                    oa0 = __builtin_amdgcn_mfma_f32_16x16x32_bf16(a1, b01, oa0, 0, 0, 0);
                    oa1 = __builtin_amdgcn_mfma_f32_16x16x32_bf16(a0, b10, oa1, 0, 0, 0);
                    oa1 = __builtin_amdgcn_mfma_f32_16x16x32_bf16(a1, b11, oa1, 0, 0, 0);
                }
            }
        }
        const int n0 = chf * 32 + l15;                // 0..15 or 32..47 (<54)
        const float bv0 = boff[n0];
        const float bv1 = (n0 + 16 < NOFF) ? boff[n0 + 16] : 0.f;
#pragma unroll
        for (int r = 0; r < 4; ++r) {
            const int p = pg * 16 + quad * 4 + r;
            offs[p * OSTR + n0] = oa0[r] + bv0;
            if (n0 + 16 < NOFF) offs[p * OSTR + n0 + 16] = oa1[r] + bv1;
        }
    }
    __syncthreads();   // offs published — the ONLY barrier in this kernel

    // ================= Phase 2: wave-autonomous deform =====================
    const int pt = wv & 1;               // position sub-tile: w0 + pt*16
    const int chh = wv >> 1;             // out-channel half: chh*32
    const int p = pt * 16 + l15;         // my position (0..31, block-local)

    floatx4 acc[2], racc[2];
#pragma unroll
    for (int g = 0; g < 2; ++g) {
        acc[g] = (floatx4){0.f, 0.f, 0.f, 0.f};
        racc[g] = (floatx4){0.f, 0.f, 0.f, 0.f};
    }

    // residual 1x1 conv (this wave's 16 pos x 32 outch)
    {
        const __hip_bfloat16* ap = xclb + (posbase + p) * C_ + quad * 8;
        const bf16x8 ra0 = *(const bf16x8*)(ap);
        const bf16x8 ra1 = *(const bf16x8*)(ap + 32);
        const __hip_bfloat16* q = wrs + chh * 2048 + lane * 8;
        const bf16x8 r00 = *(const bf16x8*)(q);
        const bf16x8 r01 = *(const bf16x8*)(q + 512);
        const bf16x8 r10 = *(const bf16x8*)(q + 1024);
        const bf16x8 r11 = *(const bf16x8*)(q + 1536);
        racc[0] = __builtin_amdgcn_mfma_f32_16x16x32_bf16(ra0, r00, racc[0], 0, 0, 0);
        racc[0] = __builtin_amdgcn_mfma_f32_16x16x32_bf16(ra1, r01, racc[0], 0, 0, 0);
        racc[1] = __builtin_amdgcn_mfma_f32_16x16x32_bf16(ra0, r10, racc[1], 0, 0, 0);
        racc[1] = __builtin_amdgcn_mfma_f32_16x16x32_bf16(ra1, r11, racc[1], 0, 0, 0);
    }

    const int k0 = (t == 0) ? 9 : 0;
    const int k1 = (t == T_ - 1) ? 18 : KTAPS;

    auto load_off = [&](int k, float& dh, float& dw) {
        dh = offs[p * OSTR + 2 * k];          // 4 quads same addr -> broadcast
        dw = offs[p * OSTR + 2 * k + 1];
    };
    // gather my A-fragment channels directly (R0 clamp+mask semantics)
    auto gather2 = [&](int k, float dh, float dw, G2& g) {
        const int kh = (k / 3) % 3, kw = k % 3;
        const float hs = (float)(h - 1 + kh) + dh;
        const float wsv = (float)(w0 + p - 1 + kw) + dw;
        const float h0f = floorf(hs), w0f = floorf(wsv);
        const float fh = hs - h0f, fw = wsv - w0f;
        const int h0i = (int)h0f, w0i = (int)w0f;
        const int h1i = h0i + 1, w1i = w0i + 1;
        const float m_h0 = ((unsigned)h0i < H_) ? 1.f : 0.f;
        const float m_h1 = ((unsigned)h1i < H_) ? 1.f : 0.f;
        const float m_w0 = ((unsigned)w0i < W_) ? 1.f : 0.f;
        const float m_w1 = ((unsigned)w1i < W_) ? 1.f : 0.f;
        g.w00 = (1.f - fh) * (1.f - fw) * m_h0 * m_w0;
        g.w01 = (1.f - fh) * fw * m_h0 * m_w1;
        g.w10 = fh * (1.f - fw) * m_h1 * m_w0;
        g.w11 = fh * fw * m_h1 * m_w1;
        const int h0c = min(max(h0i, 0), H_ - 1);
        const int h1c = min(max(h1i, 0), H_ - 1);
        const int w0c = min(max(w0i, 0), W_ - 1);
        const int w1c = min(max(w1i, 0), W_ - 1);
        const int tb = (t - 1 + k / 9) * HW_;
        const __hip_bfloat16* p00 = y1b + (tb + h0c * W_ + w0c) * C_ + quad * 8;
        const __hip_bfloat16* p01 = y1b + (tb + h0c * W_ + w1c) * C_ + quad * 8;
        const __hip_bfloat16* p10 = y1b + (tb + h1c * W_ + w0c) * C_ + quad * 8;
        const __hip_bfloat16* p11 = y1b + (tb + h1c * W_ + w1c) * C_ + quad * 8;
        g.a[0] = *(const bf16x8*)(p00);  g.b[0] = *(const bf16x8*)(p00 + 32);
        g.a[1] = *(const bf16x8*)(p01);  g.b[1] = *(const bf16x8*)(p01 + 32);
        g.a[2] = *(const bf16x8*)(p10);  g.b[2] = *(const bf16x8*)(p10 + 32);
        g.a[3] = *(const bf16x8*)(p11);  g.b[3] = *(const bf16x8*)(p11 + 32);
    };
    // blend -> two A-fragments (lo: ch quad*8, hi: ch 32+quad*8)
    auto blend2 = [&](const G2& g, bf16x8& lo, bf16x8& hi) {
        union U { bf16x8 v; __hip_bfloat16 e[8]; };
        U c0, c1, c2, c3, r;
        c0.v = g.a[0]; c1.v = g.a[1]; c2.v = g.a[2]; c3.v = g.a[3];
#pragma unroll
        for (int j = 0; j < 8; ++j) {
            float f = g.w00 * __bfloat162float(c0.e[j]) + g.w01 * __bfloat162float(c1.e[j]) +
                      g.w10 * __bfloat162float(c2.e[j]) + g.w11 * __bfloat162float(c3.e[j]);
            r.e[j] = __float2bfloat16(f);
        }
        lo = r.v;
        c0.v = g.b[0]; c1.v = g.b[1]; c2.v = g.b[2]; c3.v = g.b[3];
#pragma unroll
        for (int j = 0; j < 8; ++j) {
            float f = g.w00 * __bfloat162float(c0.e[j]) + g.w01 * __bfloat162float(c1.e[j]) +
                      g.w10 * __bfloat162float(c2.e[j]) + g.w11 * __bfloat162float(c3.e[j]);
            r.e[j] = __float2bfloat16(f);
        }
        hi = r.v;
    };
    // B-frags for this wave's 2 outch groups x 2 K-halves (same constants
    // as conv_stream's b00/b01/b10/b11)
    auto loadB2 = [&](int k, bf16x8& B00, bf16x8& B01, bf16x8& B10, bf16x8& B11) {
        const __hip_bfloat16* q = wds + k * 4096 + chh * 2048 + lane * 8;
        B00 = *(const bf16x8*)(q);
        B01 = *(const bf16x8*)(q + 512);
        B10 = *(const bf16x8*)(q + 1024);
        B11 = *(const bf16x8*)(q + 1536);
    };

    G2 gA, gB;
    bf16x8 ca0, ca1, ca2, ca3, na0, na1, na2, na3;

    {   // prologue: tap k0 in flight
        float dh, dw;
        load_off(k0, dh, dw);
        gather2(k0, dh, dw, gA);
        loadB2(k0, ca0, ca1, ca2, ca3);
    }

    int k = k0;
    for (; k + 1 < k1; k += 2) {
        {   // tap k (gA/ca); prefetch k+1 -> gB/na
            float dh, dw;
            load_off(k + 1, dh, dw);
            gather2(k + 1, dh, dw, gB);
            loadB2(k + 1, na0, na1, na2, na3);
            bf16x8 lo, hi;
            blend2(gA, lo, hi);
            acc[0] = __builtin_amdgcn_mfma_f32_16x16x32_bf16(lo, ca0, acc[0], 0, 0, 0);
            acc[0] = __builtin_amdgcn_mfma_f32_16x16x32_bf16(hi, ca1, acc[0], 0, 0, 0);
            acc[1] = __builtin_amdgcn_mfma_f32_16x16x32_bf16(lo, ca2, acc[1], 0, 0, 0);
            acc[1] = __builtin_amdgcn_mfma_f32_16x16x32_bf16(hi, ca3, acc[1], 0, 0, 0);
        }
        {   // tap k+1 (gB/na); prefetch k+2 -> gA/ca
            if (k + 2 < k1) {
                float dh, dw;
                load_off(k + 2, dh, dw);
                gather2(k + 2, dh, dw, gA);
                loadB2(k + 2, ca0, ca1, ca2, ca3);
            }
            bf16x8 lo, hi;
            blend2(gB, lo, hi);
            acc[0] = __builtin_amdgcn_mfma_f32_16x16x32_bf16(lo, na0, acc[0], 0, 0, 0);
            acc[0] = __builtin_amdgcn_mfma_f32_16x16x32_bf16(hi, na1, acc[0], 0, 0, 0);
            acc[1] = __builtin_amdgcn_mfma_f32_16x16x32_bf16(lo, na2, acc[1], 0, 0, 0);
            acc[1] = __builtin_amdgcn_mfma_f32_16x16x32_bf16(hi, na3, acc[1], 0, 0, 0);
        }
    }
    if (k < k1) {   // odd tail (interior t: 27 taps) — gA/ca valid
        bf16x8 lo, hi;
        blend2(gA, lo, hi);
        acc[0] = __builtin_amdgcn_mfma_f32_16x16x32_bf16(lo, ca0, acc[0], 0, 0, 0);
        acc[0] = __builtin_amdgcn_mfma_f32_16x16x32_bf16(hi, ca1, acc[0], 0, 0, 0);
        acc[1] = __builtin_amdgcn_mfma_f32_16x16x32_bf16(lo, ca2, acc[1], 0, 0, 0);
        acc[1] = __builtin_amdgcn_mfma_f32_16x16x32_bf16(hi, ca3, acc[1], 0, 0, 0);
    }

    // epilogue: lrelu(deform + bd) + (residual + br); wave owns its outputs
#pragma unroll
    for (int g = 0; g < 2; ++g) {
        const int n = chh * 32 + g * 16 + l15;
        const float bdv = bd[n], brv = br[n];
        floatx4 o;
#pragma unroll
        for (int r = 0; r < 4; ++r) {
            float v = acc[g][r] + bdv;
            v = (v >= 0.f) ? v : 0.01f * v;
            o[r] = v + racc[g][r] + brv;
        }
        *(floatx4*)&out[n * THW_ + posbase + pt * 16 + quad * 4] = o;
    }
}

// ---------------------------------------------------------------------------
extern "C" void kernel_launch(void* const* d_in, const int* in_sizes, int n_in,
                              void* d_out, int out_size, void* d_ws, size_t ws_size,
                              hipStream_t stream) {
    const float* x    = (const float*)d_in[0];
    const float* W1   = (const float*)d_in[1];
    const float* b1   = (const float*)d_in[2];
    const float* Woff = (const float*)d_in[3];
    const float* boff = (const float*)d_in[4];
    const float* Wd   = (const float*)d_in[5];
    const float* bd   = (const float*)d_in[6];
    const float* Wr   = (const float*)d_in[7];
    const float* br   = (const float*)d_in[8];
    float* out = (float*)d_out;

    float* ws = (float*)d_ws;
    __hip_bfloat16* xclb  = (__hip_bfloat16*)(ws);             // 2,097,152 bf16
    __hip_bfloat16* y1b   = (__hip_bfloat16*)(ws + 1048576);   // 2,097,152 bf16
    __hip_bfloat16* w1s   = (__hip_bfloat16*)(ws + 2097152);   //   110,592 bf16
    __hip_bfloat16* woffs = (__hip_bfloat16*)(ws + 2152448);   //   110,592 bf16
    __hip_bfloat16* wdsb  = (__hip_bfloat16*)(ws + 2207744);   //   110,592 bf16
    __hip_bfloat16* wrsb  = (__hip_bfloat16*)(ws + 2263040);   //     4,096 bf16
    // total ~9.1 MB

    prep_tocl_kernel<<<THW_ / 64, 256, 0, stream>>>(
        x, xclb, W1, Woff, Wd, Wr, w1s, woffs, wdsb, wrsb);

    conv_stream_kernel<<<dim3(T_ * H_ * 2), 256, 0, stream>>>(
        xclb, w1s, b1, y1b);

    deform_fused_kernel<<<dim3(T_ * H_ * 2), 256, 0, stream>>>(
        y1b, woffs, boff, wdsb, bd, xclb, wrsb, br, out);
}

// Round 7
// 220.593 us; speedup vs baseline: 1.1070x; 1.1070x over previous
//
#include <hip/hip_runtime.h>
#include <hip/hip_bf16.h>

// Problem constants (B=1)
#define T_ 8
#define H_ 64
#define W_ 64
#define C_ 64
#define HW_ (H_ * W_)          // 4096
#define THW_ (T_ * H_ * W_)    // 32768
#define KTAPS 27
#define KDIM (C_ * KTAPS)      // 1728
#define NOFF 54
#define CHS 70                 // padded LDS channel stride (bf16) for deform staging
#define OFFS_STR 56            // offsG per-position stride (bf16 elements)

typedef __bf16 bf16x8 __attribute__((ext_vector_type(8)));
typedef float floatx4 __attribute__((ext_vector_type(4)));

// Barrier that publishes LDS (ds ops) WITHOUT draining vmcnt (R1/R3-verified).
#define LGKM_BARRIER()                                        \
    do {                                                      \
        asm volatile("s_waitcnt lgkmcnt(0)" ::: "memory");    \
        __builtin_amdgcn_s_barrier();                         \
    } while (0)

// ---------------------------------------------------------------------------
// prep + to_cl merged: one launch, disjoint outputs.
// ---------------------------------------------------------------------------
__global__ __launch_bounds__(256) void prep_tocl_kernel(
    const float* __restrict__ x, __hip_bfloat16* __restrict__ xcl,
    const float* __restrict__ w1, const float* __restrict__ woff,
    const float* __restrict__ wd, const float* __restrict__ wr,
    __hip_bfloat16* __restrict__ w1s, __hip_bfloat16* __restrict__ woffs,
    __hip_bfloat16* __restrict__ wds, __hip_bfloat16* __restrict__ wrs) {
    __shared__ float tile[64][65];
    const int tid = threadIdx.x;

    {
        int i = blockIdx.x * 256 + tid;
        if (i < C_ * KDIM) {
            int j = i & 7, lane = (i >> 3) & 63, s = (i >> 9) & 1, g16 = (i >> 10) & 3, tap = i >> 12;
            int co = g16 * 16 + (lane & 15);
            int cin = s * 32 + (lane >> 4) * 8 + j;
            int src = (co * C_ + cin) * KTAPS + tap;
            w1s[i] = __float2bfloat16(w1[src]);
            woffs[i] = (co < NOFF) ? __float2bfloat16(woff[src]) : __float2bfloat16(0.f);
            wds[i] = __float2bfloat16(wd[src]);
        }
        if (i < C_ * C_) {
            int j = i & 7, lane = (i >> 3) & 63, s = (i >> 9) & 1, g16 = i >> 10;
            int co = g16 * 16 + (lane & 15);
            int cin = s * 32 + (lane >> 4) * 8 + j;
            wrs[i] = __float2bfloat16(wr[co * C_ + cin]);
        }
    }

    const int pos0 = blockIdx.x * 64;
    for (int i = tid; i < 4096; i += 256) {
        int ch = i >> 6, p = i & 63;
        tile[ch][p] = x[ch * THW_ + pos0 + p];
    }
    __syncthreads();
    for (int i = tid; i < 4096; i += 256) {
        int p = i >> 6, ch = i & 63;
        xcl[(pos0 + p) * C_ + ch] = __float2bfloat16(tile[ch][p]);
    }
}

// ---------------------------------------------------------------------------
// BARRIER-FREE per-wave streaming MFMA 3x3x3 conv (conv1) — EXACT R12 form.
// ---------------------------------------------------------------------------
__global__ __launch_bounds__(256) void conv_stream_kernel(
    const __hip_bfloat16* __restrict__ in_cl,
    const __hip_bfloat16* __restrict__ wTs,   // swizzled (27*4096)
    const float* __restrict__ bias,
    __hip_bfloat16* __restrict__ out_cl_b16) {
    __shared__ __hip_bfloat16 ts[32 * 72];    // 4608B bounce

    const int tid = threadIdx.x;
    const int wv = tid >> 6;
    const int lane = tid & 63;
    const int l15 = lane & 15;
    const int quad = lane >> 4;
    const int wh = blockIdx.x & 1;
    const int h = (blockIdx.x >> 1) & 63;
    const int t = blockIdx.x >> 7;
    const int w0 = wh * 32;
    const int pg = wv >> 1;
    const int chf = wv & 1;
    const int wpos = w0 + pg * 16 + l15;
    const int posbase = t * HW_ + h * W_;

    floatx4 acc0 = (floatx4){0.f, 0.f, 0.f, 0.f};
    floatx4 acc1 = (floatx4){0.f, 0.f, 0.f, 0.f};
    const bf16x8 z = {};
    const __hip_bfloat16* wb = wTs + chf * 2048 + lane * 8;

    const int ktlo = (t == 0) ? 1 : 0;
    const int kthi = (t == T_ - 1) ? 2 : 3;

    for (int kt = ktlo; kt < kthi; ++kt) {
        const int t_in = t - 1 + kt;
#pragma unroll 1
        for (int kh = 0; kh < 3; ++kh) {
            const int h_in = h - 1 + kh;
            if ((unsigned)h_in >= H_) continue;
            const int rowbase = t_in * HW_ + h_in * W_;
#pragma unroll
            for (int kw = 0; kw < 3; ++kw) {
                const int tap = kt * 9 + kh * 3 + kw;
                const int w_in = wpos - 1 + kw;
                const bool v = (unsigned)w_in < W_;
                const int wc = v ? w_in : 0;
                const __hip_bfloat16* ap = in_cl + (rowbase + wc) * C_ + quad * 8;
                bf16x8 a0 = *(const bf16x8*)(ap);
                bf16x8 a1 = *(const bf16x8*)(ap + 32);
                a0 = v ? a0 : z;
                a1 = v ? a1 : z;
                const __hip_bfloat16* bp = wb + tap * 4096;
                const bf16x8 b00 = *(const bf16x8*)(bp);
                const bf16x8 b01 = *(const bf16x8*)(bp + 512);
                const bf16x8 b10 = *(const bf16x8*)(bp + 1024);
                const bf16x8 b11 = *(const bf16x8*)(bp + 1536);
                acc0 = __builtin_amdgcn_mfma_f32_16x16x32_bf16(a0, b00, acc0, 0, 0, 0);
                acc0 = __builtin_amdgcn_mfma_f32_16x16x32_bf16(a1, b01, acc0, 0, 0, 0);
                acc1 = __builtin_amdgcn_mfma_f32_16x16x32_bf16(a0, b10, acc1, 0, 0, 0);
                acc1 = __builtin_amdgcn_mfma_f32_16x16x32_bf16(a1, b11, acc1, 0, 0, 0);
            }
        }
    }

    const int n0 = chf * 32 + l15;
    const float bv0 = bias[n0], bv1 = bias[n0 + 16];
#pragma unroll
    for (int r = 0; r < 4; ++r) {
        const int p = pg * 16 + quad * 4 + r;
        float v0 = acc0[r] + bv0;
        v0 = (v0 >= 0.f) ? v0 : 0.01f * v0;
        float v1 = acc1[r] + bv1;
        v1 = (v1 >= 0.f) ? v1 : 0.01f * v1;
        ts[p * 72 + n0] = __float2bfloat16(v0);
        ts[p * 72 + n0 + 16] = __float2bfloat16(v1);
    }
    __syncthreads();
    {
        const int p = tid >> 3, ck = tid & 7;
        const uint4 v4 = *(const uint4*)&ts[p * 72 + ck * 8];
        *(uint4*)&out_cl_b16[(posbase + w0 + p) * C_ + ck * 8] = v4;
    }
}

// ---------------------------------------------------------------------------
// OFFSETS conv as its own kernel (R24): the R0-verified deform phase 1 body,
// verbatim, reading y1b (the CORRECT input — R6's fusion wrongly fed x) and
// writing offsets to global bf16 (|off| ~ 0.03, bf16 abs err ~1e-4 ->
// output perturbation ~1e-3, threshold 0.1125). No LDS, no barriers.
// Splitting makes all four kernels individually visible in the profile.
// ---------------------------------------------------------------------------
__global__ __launch_bounds__(256) void offs_conv_kernel(
    const __hip_bfloat16* __restrict__ y1b,
    const __hip_bfloat16* __restrict__ woffs,  // swizzled (27*4096)
    const float* __restrict__ boff,
    __hip_bfloat16* __restrict__ offsG) {
    const int tid = threadIdx.x;
    const int wv = tid >> 6;
    const int lane = tid & 63;
    const int l15 = lane & 15;
    const int quad = lane >> 4;
    const int wh = blockIdx.x & 1;
    const int h = (blockIdx.x >> 1) & 63;
    const int t = blockIdx.x >> 7;
    const int w0 = wh * 32;
    const int pg = wv >> 1;
    const int chf = wv & 1;
    const int wpos = w0 + pg * 16 + l15;
    const int posbase = t * HW_ + h * W_;

    floatx4 oa0 = (floatx4){0.f, 0.f, 0.f, 0.f};
    floatx4 oa1 = (floatx4){0.f, 0.f, 0.f, 0.f};
    const bf16x8 z = {};
    const __hip_bfloat16* wb = woffs + chf * 2048 + lane * 8;

    const int ktlo = (t == 0) ? 1 : 0;
    const int kthi = (t == T_ - 1) ? 2 : 3;

    for (int kt = ktlo; kt < kthi; ++kt) {
        const int t_in = t - 1 + kt;
#pragma unroll 1
        for (int kh = 0; kh < 3; ++kh) {
            const int h_in = h - 1 + kh;
            if ((unsigned)h_in >= H_) continue;
            const int rowbase = t_in * HW_ + h_in * W_;
#pragma unroll
            for (int kw = 0; kw < 3; ++kw) {
                const int tap = kt * 9 + kh * 3 + kw;
                const int w_in = wpos - 1 + kw;
                const bool v = (unsigned)w_in < W_;
                const int wc = v ? w_in : 0;
                const __hip_bfloat16* ap = y1b + (rowbase + wc) * C_ + quad * 8;
                bf16x8 a0 = *(const bf16x8*)(ap);
                bf16x8 a1 = *(const bf16x8*)(ap + 32);
                a0 = v ? a0 : z;
                a1 = v ? a1 : z;
                const __hip_bfloat16* bp = wb + tap * 4096;
                const bf16x8 b00 = *(const bf16x8*)(bp);
                const bf16x8 b01 = *(const bf16x8*)(bp + 512);
                const bf16x8 b10 = *(const bf16x8*)(bp + 1024);
                const bf16x8 b11 = *(const bf16x8*)(bp + 1536);
                oa0 = __builtin_amdgcn_mfma_f32_16x16x32_bf16(a0, b00, oa0, 0, 0, 0);
                oa0 = __builtin_amdgcn_mfma_f32_16x16x32_bf16(a1, b01, oa0, 0, 0, 0);
                oa1 = __builtin_amdgcn_mfma_f32_16x16x32_bf16(a0, b10, oa1, 0, 0, 0);
                oa1 = __builtin_amdgcn_mfma_f32_16x16x32_bf16(a1, b11, oa1, 0, 0, 0);
            }
        }
    }

    const int n0 = chf * 32 + l15;                // 0..15 or 32..47 (<54)
    const float bo0 = boff[n0];
    const float bo1 = (n0 + 16 < NOFF) ? boff[n0 + 16] : 0.f;
#pragma unroll
    for (int r = 0; r < 4; ++r) {
        const int gp = posbase + w0 + pg * 16 + quad * 4 + r;
        offsG[gp * OFFS_STR + n0] = __float2bfloat16(oa0[r] + bo0);
        if (n0 + 16 < NOFF)
            offsG[gp * OFFS_STR + n0 + 16] = __float2bfloat16(oa1[r] + bo1);
    }
}

// ---------------------------------------------------------------------------
// Pure deformable-gather + 1x1 residual kernel (R24 = R6's gather kernel,
// which was structurally correct — only its offsG input was computed from
// the wrong tensor). Pipeline = R3-verified 3-panel 3-deep, verbatim.
// ---------------------------------------------------------------------------
struct Gath {
    bf16x8 c00, c01, c10, c11;
    float w00, w01, w10, w11;
};

__global__ __launch_bounds__(256) void deform_gather_kernel(
    const __hip_bfloat16* __restrict__ y1b,
    const __hip_bfloat16* __restrict__ offsG,
    const __hip_bfloat16* __restrict__ wds, const float* __restrict__ bd,
    const __hip_bfloat16* __restrict__ xclb, const __hip_bfloat16* __restrict__ wrs,
    const float* __restrict__ br, float* __restrict__ out) {
    __shared__ __hip_bfloat16 Abuf[3][32 * CHS];     // 13440 B (3 panels)

    const int tid = threadIdx.x;
    const int wv = tid >> 6;
    const int lane = tid & 63;
    const int l15 = lane & 15;
    const int quad = lane >> 4;
    const int wh = blockIdx.x & 1;
    const int h = (blockIdx.x >> 1) & 63;
    const int t = blockIdx.x >> 7;
    const int w0 = wh * 32;
    const int n = wv * 16 + l15;
    const int posbase = t * HW_ + h * W_ + w0;
    const int cpos = tid >> 3;               // position 0..31
    const int c8 = tid & 7;                  // 8-ch chunk

    floatx4 acc[2], racc[2];
#pragma unroll
    for (int m = 0; m < 2; ++m) {
        acc[m] = (floatx4){0.f, 0.f, 0.f, 0.f};
        racc[m] = (floatx4){0.f, 0.f, 0.f, 0.f};
    }

    // residual 1x1 conv on x (swizzled B, coalesced)
    {
        const bf16x8 rb0 = *(const bf16x8*)(wrs + wv * 1024 + lane * 8);
        const bf16x8 rb1 = *(const bf16x8*)(wrs + wv * 1024 + lane * 8 + 512);
#pragma unroll
        for (int m = 0; m < 2; ++m) {
            const __hip_bfloat16* ap = xclb + (posbase + m * 16 + l15) * C_ + quad * 8;
            const bf16x8 a0 = *(const bf16x8*)(ap);
            const bf16x8 a1 = *(const bf16x8*)(ap + 32);
            racc[m] = __builtin_amdgcn_mfma_f32_16x16x32_bf16(a0, rb0, racc[m], 0, 0, 0);
            racc[m] = __builtin_amdgcn_mfma_f32_16x16x32_bf16(a1, rb1, racc[m], 0, 0, 0);
        }
    }

    const int k0 = (t == 0) ? 9 : 0;
    const int k1 = (t == T_ - 1) ? 18 : KTAPS;   // k1-k0 in {18, 27}: %3 == 0

    auto load_off = [&](int k, float& dh, float& dw) {
        // one aligned 4B load -> two bf16 (channels 2k, 2k+1)
        const uint v = *(const uint*)&offsG[(posbase + cpos) * OFFS_STR + 2 * k];
        union { uint u; __hip_bfloat16 b[2]; } cv;
        cv.u = v;
        dh = __bfloat162float(cv.b[0]);
        dw = __bfloat162float(cv.b[1]);
    };
    auto gather = [&](int k, float dh, float dw, Gath& g) {
        const int kh = (k / 3) % 3, kw = k % 3;
        const float hs = (float)(h - 1 + kh) + dh;
        const float wsv = (float)(w0 + cpos - 1 + kw) + dw;
        const float h0f = floorf(hs), w0f = floorf(wsv);
        const float fh = hs - h0f, fw = wsv - w0f;
        const int h0i = (int)h0f, w0i = (int)w0f;
        const int h1i = h0i + 1, w1i = w0i + 1;
        const float m_h0 = ((unsigned)h0i < H_) ? 1.f : 0.f;
        const float m_h1 = ((unsigned)h1i < H_) ? 1.f : 0.f;
        const float m_w0 = ((unsigned)w0i < W_) ? 1.f : 0.f;
        const float m_w1 = ((unsigned)w1i < W_) ? 1.f : 0.f;
        g.w00 = (1.f - fh) * (1.f - fw) * m_h0 * m_w0;
        g.w01 = (1.f - fh) * fw * m_h0 * m_w1;
        g.w10 = fh * (1.f - fw) * m_h1 * m_w0;
        g.w11 = fh * fw * m_h1 * m_w1;
        const int h0c = min(max(h0i, 0), H_ - 1);
        const int h1c = min(max(h1i, 0), H_ - 1);
        const int w0c = min(max(w0i, 0), W_ - 1);
        const int w1c = min(max(w1i, 0), W_ - 1);
        const int tb = (t - 1 + k / 9) * HW_;
        g.c00 = *(const bf16x8*)(y1b + (tb + h0c * W_ + w0c) * C_ + c8 * 8);
        g.c01 = *(const bf16x8*)(y1b + (tb + h0c * W_ + w1c) * C_ + c8 * 8);
        g.c10 = *(const bf16x8*)(y1b + (tb + h1c * W_ + w0c) * C_ + c8 * 8);
        g.c11 = *(const bf16x8*)(y1b + (tb + h1c * W_ + w1c) * C_ + c8 * 8);
    };
    auto blend = [&](const Gath& g, bf16x8& o) {
        union U { bf16x8 v; __hip_bfloat16 e[8]; };
        U a00, a01, a10, a11, r;
        a00.v = g.c00; a01.v = g.c01; a10.v = g.c10; a11.v = g.c11;
#pragma unroll
        for (int j = 0; j < 8; ++j) {
            float f = g.w00 * __bfloat162float(a00.e[j]) + g.w01 * __bfloat162float(a01.e[j]) +
                      g.w10 * __bfloat162float(a10.e[j]) + g.w11 * __bfloat162float(a11.e[j]);
            r.e[j] = __float2bfloat16(f);
        }
        o = r.v;
    };
    auto loadBd = [&](int k, bf16x8& B0, bf16x8& B1) {
        const __hip_bfloat16* p = wds + k * 4096 + wv * 1024 + lane * 8;
        B0 = *(const bf16x8*)(p);
        B1 = *(const bf16x8*)(p + 512);
    };

    // named pipeline state: 3 Gath slots, 3 B-reg slots (no copies)
    Gath g0, g1, g2;
    bf16x8 wa0, wa1, wb0, wb1, wc0, wc1;

    // step(k): barrier -> MFMA(k) from pRead -> issue gather(k+3) into gFill
    //          -> blend(k+1) from gBlend -> store pWrite -> loadBd(k+2) bFill
    auto step = [&](int k, const __hip_bfloat16* pRead, __hip_bfloat16* pWrite,
                    Gath& gFill, Gath& gBlend,
                    bf16x8& bu0, bf16x8& bu1, bf16x8& bf0, bf16x8& bf1) {
        LGKM_BARRIER();                           // publishes store(k); vmem stays in flight

        const bf16x8 b0 = bu0;
        const bf16x8 b1 = bu1;
#pragma unroll
        for (int m = 0; m < 2; ++m) {
            const __hip_bfloat16* ap = pRead + (m * 16 + l15) * CHS + quad * 8;
            const bf16x8 a0 = *(const bf16x8*)(ap);
            const bf16x8 a1 = *(const bf16x8*)(ap + 32);
            acc[m] = __builtin_amdgcn_mfma_f32_16x16x32_bf16(a0, b0, acc[m], 0, 0, 0);
            acc[m] = __builtin_amdgcn_mfma_f32_16x16x32_bf16(a1, b1, acc[m], 0, 0, 0);
        }
        if (k + 3 < k1) {
            float dh, dw;
            load_off(k + 3, dh, dw);
            gather(k + 3, dh, dw, gFill);         // rides across next 2 barriers
        }
        if (k + 1 < k1) {
            bf16x8 bl;
            blend(gBlend, bl);                    // consumes gather(k+1)
            *(bf16x8*)&pWrite[cpos * CHS + c8 * 8] = bl;
            if (k + 2 < k1) loadBd(k + 2, bf0, bf1);
        }
    };

    // prologue: gathers 3 taps deep, B 2 deep; store tap-k0 panel pre-loop
    {
        float dh, dw;
        load_off(k0, dh, dw);
        gather(k0, dh, dw, g0);
        load_off(k0 + 1, dh, dw);
        gather(k0 + 1, dh, dw, g1);
        load_off(k0 + 2, dh, dw);
        gather(k0 + 2, dh, dw, g2);
        loadBd(k0, wa0, wa1);
        loadBd(k0 + 1, wb0, wb1);
        bf16x8 bl;
        blend(g0, bl);
        *(bf16x8*)&Abuf[0][cpos * CHS + c8 * 8] = bl;
    }

    // main loop, 3x unrolled (tap count divisible by 3, no tail)
    for (int k = k0; k < k1; k += 3) {
        step(k,     Abuf[0], Abuf[1], g0, g1, wa0, wa1, wc0, wc1);
        step(k + 1, Abuf[1], Abuf[2], g1, g2, wb0, wb1, wa0, wa1);
        step(k + 2, Abuf[2], Abuf[0], g2, g0, wc0, wc1, wb0, wb1);
    }

    // epilogue: lrelu(deform + bd) + (residual + br)
    const float bdv = bd[n];
    const float brv = br[n];
#pragma unroll
    for (int m = 0; m < 2; ++m) {
        floatx4 o;
#pragma unroll
        for (int r = 0; r < 4; ++r) {
            float v = acc[m][r] + bdv;
            v = (v >= 0.f) ? v : 0.01f * v;
            o[r] = v + racc[m][r] + brv;
        }
        *(floatx4*)&out[n * THW_ + posbase + m * 16 + quad * 4] = o;
    }
}

// ---------------------------------------------------------------------------
extern "C" void kernel_launch(void* const* d_in, const int* in_sizes, int n_in,
                              void* d_out, int out_size, void* d_ws, size_t ws_size,
                              hipStream_t stream) {
    const float* x    = (const float*)d_in[0];
    const float* W1   = (const float*)d_in[1];
    const float* b1   = (const float*)d_in[2];
    const float* Woff = (const float*)d_in[3];
    const float* boff = (const float*)d_in[4];
    const float* Wd   = (const float*)d_in[5];
    const float* bd   = (const float*)d_in[6];
    const float* Wr   = (const float*)d_in[7];
    const float* br   = (const float*)d_in[8];
    float* out = (float*)d_out;

    float* ws = (float*)d_ws;
    __hip_bfloat16* xclb  = (__hip_bfloat16*)(ws);             // 2,097,152 bf16
    __hip_bfloat16* y1b   = (__hip_bfloat16*)(ws + 1048576);   // 2,097,152 bf16
    __hip_bfloat16* w1s   = (__hip_bfloat16*)(ws + 2097152);   //   110,592 bf16
    __hip_bfloat16* woffs = (__hip_bfloat16*)(ws + 2152448);   //   110,592 bf16
    __hip_bfloat16* wdsb  = (__hip_bfloat16*)(ws + 2207744);   //   110,592 bf16
    __hip_bfloat16* wrsb  = (__hip_bfloat16*)(ws + 2263040);   //     4,096 bf16
    __hip_bfloat16* offsG = (__hip_bfloat16*)(ws + 2265088);   // 1,835,008 bf16 (32768*56)
    // total ~12.7 MB

    prep_tocl_kernel<<<THW_ / 64, 256, 0, stream>>>(
        x, xclb, W1, Woff, Wd, Wr, w1s, woffs, wdsb, wrsb);

    conv_stream_kernel<<<dim3(T_ * H_ * 2), 256, 0, stream>>>(
        xclb, w1s, b1, y1b);

    offs_conv_kernel<<<dim3(T_ * H_ * 2), 256, 0, stream>>>(
        y1b, woffs, boff, offsG);

    deform_gather_kernel<<<dim3(T_ * H_ * 2), 256, 0, stream>>>(
        y1b, offsG, wdsb, bd, xclb, wrsb, br, out);
}

// Round 10
// 200.424 us; speedup vs baseline: 1.2183x; 1.1006x over previous
//
#include <hip/hip_runtime.h>
#include <hip/hip_bf16.h>

// Problem constants (B=1)
#define T_ 8
#define H_ 64
#define W_ 64
#define C_ 64
#define HW_ (H_ * W_)          // 4096
#define THW_ (T_ * H_ * W_)    // 32768
#define KTAPS 27
#define KDIM (C_ * KTAPS)      // 1728
#define NOFF 54
#define CHS 70                 // padded LDS channel stride (bf16) for deform staging
#define OSTR 56                // LDS offsets panel stride (floats)

typedef __bf16 bf16x8 __attribute__((ext_vector_type(8)));
typedef float floatx4 __attribute__((ext_vector_type(4)));

// Barrier that publishes LDS (ds ops) WITHOUT draining vmcnt (R1/R3-verified).
#define LGKM_BARRIER()                                        \
    do {                                                      \
        asm volatile("s_waitcnt lgkmcnt(0)" ::: "memory");    \
        __builtin_amdgcn_s_barrier();                         \
    } while (0)

// h-stripe XCD swizzle (R25): hardware maps block -> XCD as bid%8 (evidence:
// R1's t-major swizzle cut FETCH 12.6->9.35MB exactly as an %8 model
// predicts). We want XCD = h>>3 so each XCD's L2 holds a 12-row h-slab of
// y1b/xclb across ALL t (~2MB << 4MB), with a perfectly balanced t-mix
// (16 blocks of every t per XCD; t-major's 18-vs-27-tap imbalance was R1's
// regression cause). Encoding: bid = (t*16 + (h&7)*2 + wh)*8 + (h>>3).
#define DECODE_SWZ(bid, t, h, wh)                             \
    const int hi3_ = (bid) & 7;                               \
    const int rest_ = (bid) >> 3;                             \
    const int wh = rest_ & 1;                                 \
    const int h = hi3_ * 8 + ((rest_ >> 1) & 7);              \
    const int t = rest_ >> 4;

// ---------------------------------------------------------------------------
// prep + to_cl merged: one launch, disjoint outputs.
// ---------------------------------------------------------------------------
__global__ __launch_bounds__(256) void prep_tocl_kernel(
    const float* __restrict__ x, __hip_bfloat16* __restrict__ xcl,
    const float* __restrict__ w1, const float* __restrict__ woff,
    const float* __restrict__ wd, const float* __restrict__ wr,
    __hip_bfloat16* __restrict__ w1s, __hip_bfloat16* __restrict__ woffs,
    __hip_bfloat16* __restrict__ wds, __hip_bfloat16* __restrict__ wrs) {
    __shared__ float tile[64][65];
    const int tid = threadIdx.x;

    {
        int i = blockIdx.x * 256 + tid;
        if (i < C_ * KDIM) {
            int j = i & 7, lane = (i >> 3) & 63, s = (i >> 9) & 1, g16 = (i >> 10) & 3, tap = i >> 12;
            int co = g16 * 16 + (lane & 15);
            int cin = s * 32 + (lane >> 4) * 8 + j;
            int src = (co * C_ + cin) * KTAPS + tap;
            w1s[i] = __float2bfloat16(w1[src]);
            woffs[i] = (co < NOFF) ? __float2bfloat16(woff[src]) : __float2bfloat16(0.f);
            wds[i] = __float2bfloat16(wd[src]);
        }
        if (i < C_ * C_) {
            int j = i & 7, lane = (i >> 3) & 63, s = (i >> 9) & 1, g16 = i >> 10;
            int co = g16 * 16 + (lane & 15);
            int cin = s * 32 + (lane >> 4) * 8 + j;
            wrs[i] = __float2bfloat16(wr[co * C_ + cin]);
        }
    }

    const int pos0 = blockIdx.x * 64;
    for (int i = tid; i < 4096; i += 256) {
        int ch = i >> 6, p = i & 63;
        tile[ch][p] = x[ch * THW_ + pos0 + p];
    }
    __syncthreads();
    for (int i = tid; i < 4096; i += 256) {
        int p = i >> 6, ch = i & 63;
        xcl[(pos0 + p) * C_ + ch] = __float2bfloat16(tile[ch][p]);
    }
}

// ---------------------------------------------------------------------------
// BARRIER-FREE per-wave streaming MFMA 3x3x3 conv (conv1) — R12 body,
// h-stripe XCD swizzle decode only.
// ---------------------------------------------------------------------------
__global__ __launch_bounds__(256) void conv_stream_kernel(
    const __hip_bfloat16* __restrict__ in_cl,
    const __hip_bfloat16* __restrict__ wTs,   // swizzled (27*4096)
    const float* __restrict__ bias,
    __hip_bfloat16* __restrict__ out_cl_b16) {
    __shared__ __hip_bfloat16 ts[32 * 72];    // 4608B bounce

    const int tid = threadIdx.x;
    const int wv = tid >> 6;
    const int lane = tid & 63;
    const int l15 = lane & 15;
    const int quad = lane >> 4;
    DECODE_SWZ(blockIdx.x, t, h, wh)
    const int w0 = wh * 32;
    const int pg = wv >> 1;
    const int chf = wv & 1;
    const int wpos = w0 + pg * 16 + l15;
    const int posbase = t * HW_ + h * W_;

    floatx4 acc0 = (floatx4){0.f, 0.f, 0.f, 0.f};
    floatx4 acc1 = (floatx4){0.f, 0.f, 0.f, 0.f};
    const bf16x8 z = {};
    const __hip_bfloat16* wb = wTs + chf * 2048 + lane * 8;

    const int ktlo = (t == 0) ? 1 : 0;
    const int kthi = (t == T_ - 1) ? 2 : 3;

    for (int kt = ktlo; kt < kthi; ++kt) {
        const int t_in = t - 1 + kt;
#pragma unroll 1
        for (int kh = 0; kh < 3; ++kh) {
            const int h_in = h - 1 + kh;
            if ((unsigned)h_in >= H_) continue;
            const int rowbase = t_in * HW_ + h_in * W_;
#pragma unroll
            for (int kw = 0; kw < 3; ++kw) {
                const int tap = kt * 9 + kh * 3 + kw;
                const int w_in = wpos - 1 + kw;
                const bool v = (unsigned)w_in < W_;
                const int wc = v ? w_in : 0;
                const __hip_bfloat16* ap = in_cl + (rowbase + wc) * C_ + quad * 8;
                bf16x8 a0 = *(const bf16x8*)(ap);
                bf16x8 a1 = *(const bf16x8*)(ap + 32);
                a0 = v ? a0 : z;
                a1 = v ? a1 : z;
                const __hip_bfloat16* bp = wb + tap * 4096;
                const bf16x8 b00 = *(const bf16x8*)(bp);
                const bf16x8 b01 = *(const bf16x8*)(bp + 512);
                const bf16x8 b10 = *(const bf16x8*)(bp + 1024);
                const bf16x8 b11 = *(const bf16x8*)(bp + 1536);
                acc0 = __builtin_amdgcn_mfma_f32_16x16x32_bf16(a0, b00, acc0, 0, 0, 0);
                acc0 = __builtin_amdgcn_mfma_f32_16x16x32_bf16(a1, b01, acc0, 0, 0, 0);
                acc1 = __builtin_amdgcn_mfma_f32_16x16x32_bf16(a0, b10, acc1, 0, 0, 0);
                acc1 = __builtin_amdgcn_mfma_f32_16x16x32_bf16(a1, b11, acc1, 0, 0, 0);
            }
        }
    }

    const int n0 = chf * 32 + l15;
    const float bv0 = bias[n0], bv1 = bias[n0 + 16];
#pragma unroll
    for (int r = 0; r < 4; ++r) {
        const int p = pg * 16 + quad * 4 + r;
        float v0 = acc0[r] + bv0;
        v0 = (v0 >= 0.f) ? v0 : 0.01f * v0;
        float v1 = acc1[r] + bv1;
        v1 = (v1 >= 0.f) ? v1 : 0.01f * v1;
        ts[p * 72 + n0] = __float2bfloat16(v0);
        ts[p * 72 + n0 + 16] = __float2bfloat16(v1);
    }
    __syncthreads();
    {
        const int p = tid >> 3, ck = tid & 7;
        const uint4 v4 = *(const uint4*)&ts[p * 72 + ck * 8];
        *(uint4*)&out_cl_b16[(posbase + w0 + p) * C_ + ck * 8] = v4;
    }
}

// ---------------------------------------------------------------------------
// FUSED offsets-conv + deformable conv + 1x1 residual — EXACT R3 body
// (verified, 200.7 total), h-stripe XCD swizzle decode only.
// ---------------------------------------------------------------------------
struct Gath {
    bf16x8 c00, c01, c10, c11;
    float w00, w01, w10, w11;
};

__global__ __launch_bounds__(256) void deform_fused_kernel(
    const __hip_bfloat16* __restrict__ y1b,
    const __hip_bfloat16* __restrict__ woffs, const float* __restrict__ boff,
    const __hip_bfloat16* __restrict__ wds, const float* __restrict__ bd,
    const __hip_bfloat16* __restrict__ xclb, const __hip_bfloat16* __restrict__ wrs,
    const float* __restrict__ br, float* __restrict__ out) {
    __shared__ __hip_bfloat16 Abuf[3][32 * CHS];     // 13440 B (3 panels)
    __shared__ float offs[32 * OSTR];                // 7168 B

    const int tid = threadIdx.x;
    const int wv = tid >> 6;
    const int lane = tid & 63;
    const int l15 = lane & 15;
    const int quad = lane >> 4;
    DECODE_SWZ(blockIdx.x, t, h, wh)
    const int w0 = wh * 32;
    const int n = wv * 16 + l15;
    const int posbase = t * HW_ + h * W_ + w0;
    const int cpos = tid >> 3;               // position 0..31
    const int c8 = tid & 7;                  // 8-ch chunk

    // ================= Phase 1: offsets conv -> LDS (R12) =================
    {
        const int pg = wv >> 1;
        const int chf = wv & 1;
        const int wpos = w0 + pg * 16 + l15;
        floatx4 oa0 = (floatx4){0.f, 0.f, 0.f, 0.f};
        floatx4 oa1 = (floatx4){0.f, 0.f, 0.f, 0.f};
        const bf16x8 z = {};
        const __hip_bfloat16* wb = woffs + chf * 2048 + lane * 8;
        const int ktlo = (t == 0) ? 1 : 0;
        const int kthi = (t == T_ - 1) ? 2 : 3;

        for (int kt = ktlo; kt < kthi; ++kt) {
            const int t_in = t - 1 + kt;
#pragma unroll 1
            for (int kh = 0; kh < 3; ++kh) {
                const int h_in = h - 1 + kh;
                if ((unsigned)h_in >= H_) continue;
                const int rowbase = t_in * HW_ + h_in * W_;
#pragma unroll
                for (int kw = 0; kw < 3; ++kw) {
                    const int tap = kt * 9 + kh * 3 + kw;
                    const int w_in = wpos - 1 + kw;
                    const bool v = (unsigned)w_in < W_;
                    const int wc = v ? w_in : 0;
                    const __hip_bfloat16* ap = y1b + (rowbase + wc) * C_ + quad * 8;
                    bf16x8 a0 = *(const bf16x8*)(ap);
                    bf16x8 a1 = *(const bf16x8*)(ap + 32);
                    a0 = v ? a0 : z;
                    a1 = v ? a1 : z;
                    const __hip_bfloat16* bp = wb + tap * 4096;
                    const bf16x8 b00 = *(const bf16x8*)(bp);
                    const bf16x8 b01 = *(const bf16x8*)(bp + 512);
                    const bf16x8 b10 = *(const bf16x8*)(bp + 1024);
                    const bf16x8 b11 = *(const bf16x8*)(bp + 1536);
                    oa0 = __builtin_amdgcn_mfma_f32_16x16x32_bf16(a0, b00, oa0, 0, 0, 0);
                    oa0 = __builtin_amdgcn_mfma_f32_16x16x32_bf16(a1, b01, oa0, 0, 0, 0);
                    oa1 = __builtin_amdgcn_mfma_f32_16x16x32_bf16(a0, b10, oa1, 0, 0, 0);
                    oa1 = __builtin_amdgcn_mfma_f32_16x16x32_bf16(a1, b11, oa1, 0, 0, 0);
                }
            }
        }
        const int n0 = chf * 32 + l15;                // 0..15 or 32..47 (<54)
        const float bv0 = boff[n0];
        const float bv1 = (n0 + 16 < NOFF) ? boff[n0 + 16] : 0.f;
#pragma unroll
        for (int r = 0; r < 4; ++r) {
            const int p = pg * 16 + quad * 4 + r;
            offs[p * OSTR + n0] = oa0[r] + bv0;
            if (n0 + 16 < NOFF) offs[p * OSTR + n0 + 16] = oa1[r] + bv1;
        }
    }
    __syncthreads();

    // ================= Phase 2: 3-deep pipelined deform (R3) ===============
    floatx4 acc[2], racc[2];
#pragma unroll
    for (int m = 0; m < 2; ++m) {
        acc[m] = (floatx4){0.f, 0.f, 0.f, 0.f};
        racc[m] = (floatx4){0.f, 0.f, 0.f, 0.f};
    }

    // residual 1x1 conv on x (swizzled B, coalesced)
    {
        const bf16x8 rb0 = *(const bf16x8*)(wrs + wv * 1024 + lane * 8);
        const bf16x8 rb1 = *(const bf16x8*)(wrs + wv * 1024 + lane * 8 + 512);
#pragma unroll
        for (int m = 0; m < 2; ++m) {
            const __hip_bfloat16* ap = xclb + (posbase + m * 16 + l15) * C_ + quad * 8;
            const bf16x8 a0 = *(const bf16x8*)(ap);
            const bf16x8 a1 = *(const bf16x8*)(ap + 32);
            racc[m] = __builtin_amdgcn_mfma_f32_16x16x32_bf16(a0, rb0, racc[m], 0, 0, 0);
            racc[m] = __builtin_amdgcn_mfma_f32_16x16x32_bf16(a1, rb1, racc[m], 0, 0, 0);
        }
    }

    const int k0 = (t == 0) ? 9 : 0;
    const int k1 = (t == T_ - 1) ? 18 : KTAPS;   // k1-k0 in {18, 27}: %3 == 0

    auto load_off = [&](int k, float& dh, float& dw) {
        dh = offs[cpos * OSTR + 2 * k];
        dw = offs[cpos * OSTR + 2 * k + 1];
    };
    auto gather = [&](int k, float dh, float dw, Gath& g) {
        const int kh = (k / 3) % 3, kw = k % 3;
        const float hs = (float)(h - 1 + kh) + dh;
        const float wsv = (float)(w0 + cpos - 1 + kw) + dw;
        const float h0f = floorf(hs), w0f = floorf(wsv);
        const float fh = hs - h0f, fw = wsv - w0f;
        const int h0i = (int)h0f, w0i = (int)w0f;
        const int h1i = h0i + 1, w1i = w0i + 1;
        const float m_h0 = ((unsigned)h0i < H_) ? 1.f : 0.f;
        const float m_h1 = ((unsigned)h1i < H_) ? 1.f : 0.f;
        const float m_w0 = ((unsigned)w0i < W_) ? 1.f : 0.f;
        const float m_w1 = ((unsigned)w1i < W_) ? 1.f : 0.f;
        g.w00 = (1.f - fh) * (1.f - fw) * m_h0 * m_w0;
        g.w01 = (1.f - fh) * fw * m_h0 * m_w1;
        g.w10 = fh * (1.f - fw) * m_h1 * m_w0;
        g.w11 = fh * fw * m_h1 * m_w1;
        const int h0c = min(max(h0i, 0), H_ - 1);
        const int h1c = min(max(h1i, 0), H_ - 1);
        const int w0c = min(max(w0i, 0), W_ - 1);
        const int w1c = min(max(w1i, 0), W_ - 1);
        const int tb = (t - 1 + k / 9) * HW_;
        g.c00 = *(const bf16x8*)(y1b + (tb + h0c * W_ + w0c) * C_ + c8 * 8);
        g.c01 = *(const bf16x8*)(y1b + (tb + h0c * W_ + w1c) * C_ + c8 * 8);
        g.c10 = *(const bf16x8*)(y1b + (tb + h1c * W_ + w0c) * C_ + c8 * 8);
        g.c11 = *(const bf16x8*)(y1b + (tb + h1c * W_ + w1c) * C_ + c8 * 8);
    };
    auto blend = [&](const Gath& g, bf16x8& o) {
        union U { bf16x8 v; __hip_bfloat16 e[8]; };
        U a00, a01, a10, a11, r;
        a00.v = g.c00; a01.v = g.c01; a10.v = g.c10; a11.v = g.c11;
#pragma unroll
        for (int j = 0; j < 8; ++j) {
            float f = g.w00 * __bfloat162float(a00.e[j]) + g.w01 * __bfloat162float(a01.e[j]) +
                      g.w10 * __bfloat162float(a10.e[j]) + g.w11 * __bfloat162float(a11.e[j]);
            r.e[j] = __float2bfloat16(f);
        }
        o = r.v;
    };
    auto loadBd = [&](int k, bf16x8& B0, bf16x8& B1) {
        const __hip_bfloat16* p = wds + k * 4096 + wv * 1024 + lane * 8;
        B0 = *(const bf16x8*)(p);
        B1 = *(const bf16x8*)(p + 512);
    };

    // named pipeline state: 3 Gath slots, 3 B-reg slots (no copies)
    Gath g0, g1, g2;
    bf16x8 wa0, wa1, wb0, wb1, wc0, wc1;

    auto step = [&](int k, const __hip_bfloat16* pRead, __hip_bfloat16* pWrite,
                    Gath& gFill, Gath& gBlend,
                    bf16x8& bu0, bf16x8& bu1, bf16x8& bf0, bf16x8& bf1) {
        LGKM_BARRIER();                           // publishes store(k); vmem stays in flight

        const bf16x8 b0 = bu0;
        const bf16x8 b1 = bu1;
#pragma unroll
        for (int m = 0; m < 2; ++m) {
            const __hip_bfloat16* ap = pRead + (m * 16 + l15) * CHS + quad * 8;
            const bf16x8 a0 = *(const bf16x8*)(ap);
            const bf16x8 a1 = *(const bf16x8*)(ap + 32);
            acc[m] = __builtin_amdgcn_mfma_f32_16x16x32_bf16(a0, b0, acc[m], 0, 0, 0);
            acc[m] = __builtin_amdgcn_mfma_f32_16x16x32_bf16(a1, b1, acc[m], 0, 0, 0);
        }
        if (k + 3 < k1) {
            float dh, dw;
            load_off(k + 3, dh, dw);
            gather(k + 3, dh, dw, gFill);         // rides across next 2 barriers
        }
        if (k + 1 < k1) {
            bf16x8 bl;
            blend(gBlend, bl);                    // consumes gather(k+1)
            *(bf16x8*)&pWrite[cpos * CHS + c8 * 8] = bl;
            if (k + 2 < k1) loadBd(k + 2, bf0, bf1);
        }
    };

    // prologue: gathers 3 taps deep, B 2 deep; store tap-k0 panel pre-loop
    {
        float dh, dw;
        load_off(k0, dh, dw);
        gather(k0, dh, dw, g0);
        load_off(k0 + 1, dh, dw);
        gather(k0 + 1, dh, dw, g1);
        load_off(k0 + 2, dh, dw);
        gather(k0 + 2, dh, dw, g2);
        loadBd(k0, wa0, wa1);
        loadBd(k0 + 1, wb0, wb1);
        bf16x8 bl;
        blend(g0, bl);
        *(bf16x8*)&Abuf[0][cpos * CHS + c8 * 8] = bl;
    }

    // main loop, 3x unrolled (tap count divisible by 3, no tail)
    for (int k = k0; k < k1; k += 3) {
        step(k,     Abuf[0], Abuf[1], g0, g1, wa0, wa1, wc0, wc1);
        step(k + 1, Abuf[1], Abuf[2], g1, g2, wb0, wb1, wa0, wa1);
        step(k + 2, Abuf[2], Abuf[0], g2, g0, wc0, wc1, wb0, wb1);
    }

    // epilogue: lrelu(deform + bd) + (residual + br)
    const float bdv = bd[n];
    const float brv = br[n];
#pragma unroll
    for (int m = 0; m < 2; ++m) {
        floatx4 o;
#pragma unroll
        for (int r = 0; r < 4; ++r) {
            float v = acc[m][r] + bdv;
            v = (v >= 0.f) ? v : 0.01f * v;
            o[r] = v + racc[m][r] + brv;
        }
        *(floatx4*)&out[n * THW_ + posbase + m * 16 + quad * 4] = o;
    }
}

// ---------------------------------------------------------------------------
extern "C" void kernel_launch(void* const* d_in, const int* in_sizes, int n_in,
                              void* d_out, int out_size, void* d_ws, size_t ws_size,
                              hipStream_t stream) {
    const float* x    = (const float*)d_in[0];
    const float* W1   = (const float*)d_in[1];
    const float* b1   = (const float*)d_in[2];
    const float* Woff = (const float*)d_in[3];
    const float* boff = (const float*)d_in[4];
    const float* Wd   = (const float*)d_in[5];
    const float* bd   = (const float*)d_in[6];
    const float* Wr   = (const float*)d_in[7];
    const float* br   = (const float*)d_in[8];
    float* out = (float*)d_out;

    float* ws = (float*)d_ws;
    __hip_bfloat16* xclb  = (__hip_bfloat16*)(ws);             // 2,097,152 bf16
    __hip_bfloat16* y1b   = (__hip_bfloat16*)(ws + 1048576);   // 2,097,152 bf16
    __hip_bfloat16* w1s   = (__hip_bfloat16*)(ws + 2097152);   //   110,592 bf16
    __hip_bfloat16* woffs = (__hip_bfloat16*)(ws + 2152448);   //   110,592 bf16
    __hip_bfloat16* wdsb  = (__hip_bfloat16*)(ws + 2207744);   //   110,592 bf16
    __hip_bfloat16* wrsb  = (__hip_bfloat16*)(ws + 2263040);   //     4,096 bf16
    // total ~9.1 MB

    prep_tocl_kernel<<<THW_ / 64, 256, 0, stream>>>(
        x, xclb, W1, Woff, Wd, Wr, w1s, woffs, wdsb, wrsb);

    conv_stream_kernel<<<dim3(T_ * H_ * 2), 256, 0, stream>>>(
        xclb, w1s, b1, y1b);

    deform_fused_kernel<<<dim3(T_ * H_ * 2), 256, 0, stream>>>(
        y1b, woffs, boff, wdsb, bd, xclb, wrsb, br, out);
}

// Round 11
// 200.225 us; speedup vs baseline: 1.2196x; 1.0010x over previous
//
#include <hip/hip_runtime.h>
#include <hip/hip_bf16.h>

// Problem constants (B=1)
#define T_ 8
#define H_ 64
#define W_ 64
#define C_ 64
#define HW_ (H_ * W_)          // 4096
#define THW_ (T_ * H_ * W_)    // 32768
#define KTAPS 27
#define KDIM (C_ * KTAPS)      // 1728
#define NOFF 54
#define OSTR2 58               // offs LDS stride (floats): 58%32=26 -> conflict-free l15 reads

typedef __bf16 bf16x8 __attribute__((ext_vector_type(8)));
typedef float floatx4 __attribute__((ext_vector_type(4)));

// h-stripe XCD swizzle (R10-VERIFIED: FETCH 12.6->6.8MB, time-neutral, kept
// for the HBM-traffic reduction). XCD = bid%8 = h>>3.
// conv grid 1024: bid = (t*16 + (h&7)*2 + wh)*8 + (h>>3)
#define DECODE_SWZ_CONV(bid, t, h, wh)                        \
    const int hi3_ = (bid) & 7;                               \
    const int rest_ = (bid) >> 3;                             \
    const int wh = rest_ & 1;                                 \
    const int h = hi3_ * 8 + ((rest_ >> 1) & 7);              \
    const int t = rest_ >> 4;
// deform grid 512 (full h-row blocks): bid = (t*8 + (h&7))*8 + (h>>3)
#define DECODE_SWZ_ROW(bid, t, h)                             \
    const int h = ((bid) & 7) * 8 + (((bid) >> 3) & 7);       \
    const int t = (bid) >> 6;

// ---------------------------------------------------------------------------
// prep + to_cl merged: one launch, disjoint outputs.
// ---------------------------------------------------------------------------
__global__ __launch_bounds__(256) void prep_tocl_kernel(
    const float* __restrict__ x, __hip_bfloat16* __restrict__ xcl,
    const float* __restrict__ w1, const float* __restrict__ woff,
    const float* __restrict__ wd, const float* __restrict__ wr,
    __hip_bfloat16* __restrict__ w1s, __hip_bfloat16* __restrict__ woffs,
    __hip_bfloat16* __restrict__ wds, __hip_bfloat16* __restrict__ wrs) {
    __shared__ float tile[64][65];
    const int tid = threadIdx.x;

    {
        int i = blockIdx.x * 256 + tid;
        if (i < C_ * KDIM) {
            int j = i & 7, lane = (i >> 3) & 63, s = (i >> 9) & 1, g16 = (i >> 10) & 3, tap = i >> 12;
            int co = g16 * 16 + (lane & 15);
            int cin = s * 32 + (lane >> 4) * 8 + j;
            int src = (co * C_ + cin) * KTAPS + tap;
            w1s[i] = __float2bfloat16(w1[src]);
            woffs[i] = (co < NOFF) ? __float2bfloat16(woff[src]) : __float2bfloat16(0.f);
            wds[i] = __float2bfloat16(wd[src]);
        }
        if (i < C_ * C_) {
            int j = i & 7, lane = (i >> 3) & 63, s = (i >> 9) & 1, g16 = i >> 10;
            int co = g16 * 16 + (lane & 15);
            int cin = s * 32 + (lane >> 4) * 8 + j;
            wrs[i] = __float2bfloat16(wr[co * C_ + cin]);
        }
    }

    const int pos0 = blockIdx.x * 64;
    for (int i = tid; i < 4096; i += 256) {
        int ch = i >> 6, p = i & 63;
        tile[ch][p] = x[ch * THW_ + pos0 + p];
    }
    __syncthreads();
    for (int i = tid; i < 4096; i += 256) {
        int p = i >> 6, ch = i & 63;
        xcl[(pos0 + p) * C_ + ch] = __float2bfloat16(tile[ch][p]);
    }
}

// ---------------------------------------------------------------------------
// BARRIER-FREE per-wave streaming MFMA 3x3x3 conv (conv1) — R10 verbatim.
// ---------------------------------------------------------------------------
__global__ __launch_bounds__(256) void conv_stream_kernel(
    const __hip_bfloat16* __restrict__ in_cl,
    const __hip_bfloat16* __restrict__ wTs,   // swizzled (27*4096)
    const float* __restrict__ bias,
    __hip_bfloat16* __restrict__ out_cl_b16) {
    __shared__ __hip_bfloat16 ts[32 * 72];    // 4608B bounce

    const int tid = threadIdx.x;
    const int wv = tid >> 6;
    const int lane = tid & 63;
    const int l15 = lane & 15;
    const int quad = lane >> 4;
    DECODE_SWZ_CONV(blockIdx.x, t, h, wh)
    const int w0 = wh * 32;
    const int pg = wv >> 1;
    const int chf = wv & 1;
    const int wpos = w0 + pg * 16 + l15;
    const int posbase = t * HW_ + h * W_;

    floatx4 acc0 = (floatx4){0.f, 0.f, 0.f, 0.f};
    floatx4 acc1 = (floatx4){0.f, 0.f, 0.f, 0.f};
    const bf16x8 z = {};
    const __hip_bfloat16* wb = wTs + chf * 2048 + lane * 8;

    const int ktlo = (t == 0) ? 1 : 0;
    const int kthi = (t == T_ - 1) ? 2 : 3;

    for (int kt = ktlo; kt < kthi; ++kt) {
        const int t_in = t - 1 + kt;
#pragma unroll 1
        for (int kh = 0; kh < 3; ++kh) {
            const int h_in = h - 1 + kh;
            if ((unsigned)h_in >= H_) continue;
            const int rowbase = t_in * HW_ + h_in * W_;
#pragma unroll
            for (int kw = 0; kw < 3; ++kw) {
                const int tap = kt * 9 + kh * 3 + kw;
                const int w_in = wpos - 1 + kw;
                const bool v = (unsigned)w_in < W_;
                const int wc = v ? w_in : 0;
                const __hip_bfloat16* ap = in_cl + (rowbase + wc) * C_ + quad * 8;
                bf16x8 a0 = *(const bf16x8*)(ap);
                bf16x8 a1 = *(const bf16x8*)(ap + 32);
                a0 = v ? a0 : z;
                a1 = v ? a1 : z;
                const __hip_bfloat16* bp = wb + tap * 4096;
                const bf16x8 b00 = *(const bf16x8*)(bp);
                const bf16x8 b01 = *(const bf16x8*)(bp + 512);
                const bf16x8 b10 = *(const bf16x8*)(bp + 1024);
                const bf16x8 b11 = *(const bf16x8*)(bp + 1536);
                acc0 = __builtin_amdgcn_mfma_f32_16x16x32_bf16(a0, b00, acc0, 0, 0, 0);
                acc0 = __builtin_amdgcn_mfma_f32_16x16x32_bf16(a1, b01, acc0, 0, 0, 0);
                acc1 = __builtin_amdgcn_mfma_f32_16x16x32_bf16(a0, b10, acc1, 0, 0, 0);
                acc1 = __builtin_amdgcn_mfma_f32_16x16x32_bf16(a1, b11, acc1, 0, 0, 0);
            }
        }
    }

    const int n0 = chf * 32 + l15;
    const float bv0 = bias[n0], bv1 = bias[n0 + 16];
#pragma unroll
    for (int r = 0; r < 4; ++r) {
        const int p = pg * 16 + quad * 4 + r;
        float v0 = acc0[r] + bv0;
        v0 = (v0 >= 0.f) ? v0 : 0.01f * v0;
        float v1 = acc1[r] + bv1;
        v1 = (v1 >= 0.f) ? v1 : 0.01f * v1;
        ts[p * 72 + n0] = __float2bfloat16(v0);
        ts[p * 72 + n0 + 16] = __float2bfloat16(v1);
    }
    __syncthreads();
    {
        const int p = tid >> 3, ck = tid & 7;
        const uint4 v4 = *(const uint4*)&ts[p * 72 + ck * 8];
        *(uint4*)&out_cl_b16[(posbase + w0 + p) * C_ + ck * 8] = v4;
    }
}

// ---------------------------------------------------------------------------
// FUSED offsets-conv + deform + residual, ZERO-BARRIER wave-autonomous (R26).
//  Block = one h-row (64 pos), 4 waves. Wave wv owns positions wv*16..+15
//  and ALL 64 out-channels (vs R22's pos x outch-half split, which passed
//  correctness but DUPLICATED every gather 2x -> +43us). Per position the
//  4 quad-lanes gather 2 K-half slices x 4 corners = the SAME 32 16B-request
//  count as the panel version: no duplication, no LDS panels, no transpose,
//  and NO BARRIER anywhere (phase1 offsets are per-wave, published via a
//  wave-private LDS slice + lgkmcnt(0) — same-wave visibility).
// ---------------------------------------------------------------------------
struct G2 {
    bf16x8 a[4];          // 4 bilinear corners, channels quad*8 .. +7
    bf16x8 b[4];          // 4 corners, channels 32+quad*8 .. +7
    float w00, w01, w10, w11;
};

__global__ __launch_bounds__(256) void deform_fused_kernel(
    const __hip_bfloat16* __restrict__ y1b,
    const __hip_bfloat16* __restrict__ woffs, const float* __restrict__ boff,
    const __hip_bfloat16* __restrict__ wds, const float* __restrict__ bd,
    const __hip_bfloat16* __restrict__ xclb, const __hip_bfloat16* __restrict__ wrs,
    const float* __restrict__ br, float* __restrict__ out) {
    __shared__ float offs[4][16][OSTR2];     // 14848 B, wave-private slices

    const int tid = threadIdx.x;
    const int wv = tid >> 6;
    const int lane = tid & 63;
    const int l15 = lane & 15;
    const int quad = lane >> 4;
    DECODE_SWZ_ROW(blockIdx.x, t, h)
    const int posbase = t * HW_ + h * W_;
    const int pw = wv * 16 + l15;            // this lane's position (w coord)

    const int ktlo = (t == 0) ? 1 : 0;
    const int kthi = (t == T_ - 1) ? 2 : 3;

    // ========== Phase 1: per-wave offsets conv (no barrier) ==========
    {
        floatx4 oacc[4];
#pragma unroll
        for (int g = 0; g < 4; ++g) oacc[g] = (floatx4){0.f, 0.f, 0.f, 0.f};
        const bf16x8 z = {};

        for (int kt = ktlo; kt < kthi; ++kt) {
            const int t_in = t - 1 + kt;
#pragma unroll 1
            for (int kh = 0; kh < 3; ++kh) {
                const int h_in = h - 1 + kh;
                if ((unsigned)h_in >= H_) continue;
                const int rowbase = t_in * HW_ + h_in * W_;
#pragma unroll
                for (int kw = 0; kw < 3; ++kw) {
                    const int tap = kt * 9 + kh * 3 + kw;
                    const int w_in = pw - 1 + kw;
                    const bool v = (unsigned)w_in < W_;
                    const int wc = v ? w_in : 0;
                    const __hip_bfloat16* ap = y1b + (rowbase + wc) * C_ + quad * 8;
                    bf16x8 a0 = *(const bf16x8*)(ap);
                    bf16x8 a1 = *(const bf16x8*)(ap + 32);
                    a0 = v ? a0 : z;
                    a1 = v ? a1 : z;
                    const __hip_bfloat16* op = woffs + tap * 4096 + lane * 8;
#pragma unroll
                    for (int g = 0; g < 4; ++g) {
                        const bf16x8 b0 = *(const bf16x8*)(op + g * 1024);
                        const bf16x8 b1 = *(const bf16x8*)(op + g * 1024 + 512);
                        oacc[g] = __builtin_amdgcn_mfma_f32_16x16x32_bf16(a0, b0, oacc[g], 0, 0, 0);
                        oacc[g] = __builtin_amdgcn_mfma_f32_16x16x32_bf16(a1, b1, oacc[g], 0, 0, 0);
                    }
                }
            }
        }
#pragma unroll
        for (int g = 0; g < 4; ++g) {
            const int idx = g * 16 + l15;            // offset channel
            if (idx < NOFF) {
                const float bo = boff[idx];
#pragma unroll
                for (int r = 0; r < 4; ++r)
                    offs[wv][quad * 4 + r][idx] = oacc[g][r] + bo;
            }
        }
    }
    // publish within wave: LDS ops complete in order; no cross-wave readers
    asm volatile("s_waitcnt lgkmcnt(0)" ::: "memory");

    // ========== Phase 2: barrier-free deform + residual ==========
    floatx4 acc[4], racc[4];
#pragma unroll
    for (int g = 0; g < 4; ++g) {
        acc[g] = (floatx4){0.f, 0.f, 0.f, 0.f};
        racc[g] = (floatx4){0.f, 0.f, 0.f, 0.f};
    }

    // residual 1x1 conv: this wave's 16 pos x all 64 outch
    {
        const __hip_bfloat16* ap = xclb + (posbase + pw) * C_ + quad * 8;
        const bf16x8 ra0 = *(const bf16x8*)(ap);
        const bf16x8 ra1 = *(const bf16x8*)(ap + 32);
        const __hip_bfloat16* q = wrs + lane * 8;
#pragma unroll
        for (int g = 0; g < 4; ++g) {
            const bf16x8 r0 = *(const bf16x8*)(q + g * 1024);
            const bf16x8 r1 = *(const bf16x8*)(q + g * 1024 + 512);
            racc[g] = __builtin_amdgcn_mfma_f32_16x16x32_bf16(ra0, r0, racc[g], 0, 0, 0);
            racc[g] = __builtin_amdgcn_mfma_f32_16x16x32_bf16(ra1, r1, racc[g], 0, 0, 0);
        }
    }

    const int k0 = (t == 0) ? 9 : 0;
    const int k1 = (t == T_ - 1) ? 18 : KTAPS;

    auto load_off = [&](int k, float& dh, float& dw) {
        dh = offs[wv][l15][2 * k];               // 4 quads same addr -> broadcast
        dw = offs[wv][l15][2 * k + 1];
    };
    // gather my A-fragment channels directly (R22-verified layout/semantics)
    auto gather2 = [&](int k, float dh, float dw, G2& g) {
        const int kh = (k / 3) % 3, kw = k % 3;
        const float hs = (float)(h - 1 + kh) + dh;
        const float wsv = (float)(pw - 1 + kw) + dw;
        const float h0f = floorf(hs), w0f = floorf(wsv);
        const float fh = hs - h0f, fw = wsv - w0f;
        const int h0i = (int)h0f, w0i = (int)w0f;
        const int h1i = h0i + 1, w1i = w0i + 1;
        const float m_h0 = ((unsigned)h0i < H_) ? 1.f : 0.f;
        const float m_h1 = ((unsigned)h1i < H_) ? 1.f : 0.f;
        const float m_w0 = ((unsigned)w0i < W_) ? 1.f : 0.f;
        const float m_w1 = ((unsigned)w1i < W_) ? 1.f : 0.f;
        g.w00 = (1.f - fh) * (1.f - fw) * m_h0 * m_w0;
        g.w01 = (1.f - fh) * fw * m_h0 * m_w1;
        g.w10 = fh * (1.f - fw) * m_h1 * m_w0;
        g.w11 = fh * fw * m_h1 * m_w1;
        const int h0c = min(max(h0i, 0), H_ - 1);
        const int h1c = min(max(h1i, 0), H_ - 1);
        const int w0c = min(max(w0i, 0), W_ - 1);
        const int w1c = min(max(w1i, 0), W_ - 1);
        const int tb = (t - 1 + k / 9) * HW_;
        const __hip_bfloat16* p00 = y1b + (tb + h0c * W_ + w0c) * C_ + quad * 8;
        const __hip_bfloat16* p01 = y1b + (tb + h0c * W_ + w1c) * C_ + quad * 8;
        const __hip_bfloat16* p10 = y1b + (tb + h1c * W_ + w0c) * C_ + quad * 8;
        const __hip_bfloat16* p11 = y1b + (tb + h1c * W_ + w1c) * C_ + quad * 8;
        g.a[0] = *(const bf16x8*)(p00);  g.b[0] = *(const bf16x8*)(p00 + 32);
        g.a[1] = *(const bf16x8*)(p01);  g.b[1] = *(const bf16x8*)(p01 + 32);
        g.a[2] = *(const bf16x8*)(p10);  g.b[2] = *(const bf16x8*)(p10 + 32);
        g.a[3] = *(const bf16x8*)(p11);  g.b[3] = *(const bf16x8*)(p11 + 32);
    };
    auto blend2 = [&](const G2& g, bf16x8& lo, bf16x8& hi) {
        union U { bf16x8 v; __hip_bfloat16 e[8]; };
        U c0, c1, c2, c3, r;
        c0.v = g.a[0]; c1.v = g.a[1]; c2.v = g.a[2]; c3.v = g.a[3];
#pragma unroll
        for (int j = 0; j < 8; ++j) {
            float f = g.w00 * __bfloat162float(c0.e[j]) + g.w01 * __bfloat162float(c1.e[j]) +
                      g.w10 * __bfloat162float(c2.e[j]) + g.w11 * __bfloat162float(c3.e[j]);
            r.e[j] = __float2bfloat16(f);
        }
        lo = r.v;
        c0.v = g.b[0]; c1.v = g.b[1]; c2.v = g.b[2]; c3.v = g.b[3];
#pragma unroll
        for (int j = 0; j < 8; ++j) {
            float f = g.w00 * __bfloat162float(c0.e[j]) + g.w01 * __bfloat162float(c1.e[j]) +
                      g.w10 * __bfloat162float(c2.e[j]) + g.w11 * __bfloat162float(c3.e[j]);
            r.e[j] = __float2bfloat16(f);
        }
        hi = r.v;
    };
    // one tap's MFMAs: 4 outch groups x 2 K-halves, B loaded in-tap (L2-hot,
    // latency covered by the blend VALU work issued before the MFMAs)
    auto tapMFMA = [&](int k, const bf16x8& lo, const bf16x8& hi) {
        const __hip_bfloat16* q = wds + k * 4096 + lane * 8;
#pragma unroll
        for (int g = 0; g < 4; ++g) {
            const bf16x8 b0 = *(const bf16x8*)(q + g * 1024);
            const bf16x8 b1 = *(const bf16x8*)(q + g * 1024 + 512);
            acc[g] = __builtin_amdgcn_mfma_f32_16x16x32_bf16(lo, b0, acc[g], 0, 0, 0);
            acc[g] = __builtin_amdgcn_mfma_f32_16x16x32_bf16(hi, b1, acc[g], 0, 0, 0);
        }
    };

    G2 gA, gB;
    {   // prologue: tap k0 in flight
        float dh, dw;
        load_off(k0, dh, dw);
        gather2(k0, dh, dw, gA);
    }

    int k = k0;
    for (; k + 1 < k1; k += 2) {
        {   // tap k (gA); prefetch k+1 -> gB
            float dh, dw;
            load_off(k + 1, dh, dw);
            gather2(k + 1, dh, dw, gB);
            bf16x8 lo, hi;
            blend2(gA, lo, hi);
            tapMFMA(k, lo, hi);
        }
        {   // tap k+1 (gB); prefetch k+2 -> gA
            if (k + 2 < k1) {
                float dh, dw;
                load_off(k + 2, dh, dw);
                gather2(k + 2, dh, dw, gA);
            }
            bf16x8 lo, hi;
            blend2(gB, lo, hi);
            tapMFMA(k + 1, lo, hi);
        }
    }
    if (k < k1) {   // odd tail (interior t: 27 taps) — gA valid
        bf16x8 lo, hi;
        blend2(gA, lo, hi);
        tapMFMA(k, lo, hi);
    }

    // epilogue: lrelu(deform + bd) + (residual + br); wave owns its outputs
#pragma unroll
    for (int g = 0; g < 4; ++g) {
        const int n = g * 16 + l15;
        const float bdv = bd[n], brv = br[n];
        floatx4 o;
#pragma unroll
        for (int r = 0; r < 4; ++r) {
            float v = acc[g][r] + bdv;
            v = (v >= 0.f) ? v : 0.01f * v;
            o[r] = v + racc[g][r] + brv;
        }
        *(floatx4*)&out[n * THW_ + posbase + wv * 16 + quad * 4] = o;
    }
}

// ---------------------------------------------------------------------------
extern "C" void kernel_launch(void* const* d_in, const int* in_sizes, int n_in,
                              void* d_out, int out_size, void* d_ws, size_t ws_size,
                              hipStream_t stream) {
    const float* x    = (const float*)d_in[0];
    const float* W1   = (const float*)d_in[1];
    const float* b1   = (const float*)d_in[2];
    const float* Woff = (const float*)d_in[3];
    const float* boff = (const float*)d_in[4];
    const float* Wd   = (const float*)d_in[5];
    const float* bd   = (const float*)d_in[6];
    const float* Wr   = (const float*)d_in[7];
    const float* br   = (const float*)d_in[8];
    float* out = (float*)d_out;

    float* ws = (float*)d_ws;
    __hip_bfloat16* xclb  = (__hip_bfloat16*)(ws);             // 2,097,152 bf16
    __hip_bfloat16* y1b   = (__hip_bfloat16*)(ws + 1048576);   // 2,097,152 bf16
    __hip_bfloat16* w1s   = (__hip_bfloat16*)(ws + 2097152);   //   110,592 bf16
    __hip_bfloat16* woffs = (__hip_bfloat16*)(ws + 2152448);   //   110,592 bf16
    __hip_bfloat16* wdsb  = (__hip_bfloat16*)(ws + 2207744);   //   110,592 bf16
    __hip_bfloat16* wrsb  = (__hip_bfloat16*)(ws + 2263040);   //     4,096 bf16
    // total ~9.1 MB

    prep_tocl_kernel<<<THW_ / 64, 256, 0, stream>>>(
        x, xclb, W1, Woff, Wd, Wr, w1s, woffs, wdsb, wrsb);

    conv_stream_kernel<<<dim3(T_ * H_ * 2), 256, 0, stream>>>(
        xclb, w1s, b1, y1b);

    deform_fused_kernel<<<dim3(T_ * H_), 256, 0, stream>>>(
        y1b, woffs, boff, wdsb, bd, xclb, wrsb, br, out);
}

// Round 12
// 177.924 us; speedup vs baseline: 1.3724x; 1.1253x over previous
//
#include <hip/hip_runtime.h>
#include <hip/hip_bf16.h>

// Problem constants (B=1)
#define T_ 8
#define H_ 64
#define W_ 64
#define C_ 64
#define HW_ (H_ * W_)          // 4096
#define THW_ (T_ * H_ * W_)    // 32768
#define KTAPS 27
#define KDIM (C_ * KTAPS)      // 1728
#define NOFF 54
#define OSTR2 58               // offs LDS stride (floats)

typedef __bf16 bf16x8 __attribute__((ext_vector_type(8)));
typedef float floatx4 __attribute__((ext_vector_type(4)));

#define LGKM_BARRIER()                                        \
    do {                                                      \
        asm volatile("s_waitcnt lgkmcnt(0)" ::: "memory");    \
        __builtin_amdgcn_s_barrier();                         \
    } while (0)

// h-stripe XCD swizzle (R10-VERIFIED: FETCH 12.6->6.8MB, kept).
#define DECODE_SWZ_CONV(bid, t, h, wh)                        \
    const int hi3_ = (bid) & 7;                               \
    const int rest_ = (bid) >> 3;                             \
    const int wh = rest_ & 1;                                 \
    const int h = hi3_ * 8 + ((rest_ >> 1) & 7);              \
    const int t = rest_ >> 4;
#define DECODE_SWZ_ROW(bid, t, h)                             \
    const int h = ((bid) & 7) * 8 + (((bid) >> 3) & 7);       \
    const int t = (bid) >> 6;

// ---------------------------------------------------------------------------
// prep + to_cl merged (unchanged).
// ---------------------------------------------------------------------------
__global__ __launch_bounds__(256) void prep_tocl_kernel(
    const float* __restrict__ x, __hip_bfloat16* __restrict__ xcl,
    const float* __restrict__ w1, const float* __restrict__ woff,
    const float* __restrict__ wd, const float* __restrict__ wr,
    __hip_bfloat16* __restrict__ w1s, __hip_bfloat16* __restrict__ woffs,
    __hip_bfloat16* __restrict__ wds, __hip_bfloat16* __restrict__ wrs) {
    __shared__ float tile[64][65];
    const int tid = threadIdx.x;

    {
        int i = blockIdx.x * 256 + tid;
        if (i < C_ * KDIM) {
            int j = i & 7, lane = (i >> 3) & 63, s = (i >> 9) & 1, g16 = (i >> 10) & 3, tap = i >> 12;
            int co = g16 * 16 + (lane & 15);
            int cin = s * 32 + (lane >> 4) * 8 + j;
            int src = (co * C_ + cin) * KTAPS + tap;
            w1s[i] = __float2bfloat16(w1[src]);
            woffs[i] = (co < NOFF) ? __float2bfloat16(woff[src]) : __float2bfloat16(0.f);
            wds[i] = __float2bfloat16(wd[src]);
        }
        if (i < C_ * C_) {
            int j = i & 7, lane = (i >> 3) & 63, s = (i >> 9) & 1, g16 = i >> 10;
            int co = g16 * 16 + (lane & 15);
            int cin = s * 32 + (lane >> 4) * 8 + j;
            wrs[i] = __float2bfloat16(wr[co * C_ + cin]);
        }
    }

    const int pos0 = blockIdx.x * 64;
    for (int i = tid; i < 4096; i += 256) {
        int ch = i >> 6, p = i & 63;
        tile[ch][p] = x[ch * THW_ + pos0 + p];
    }
    __syncthreads();
    for (int i = tid; i < 4096; i += 256) {
        int p = i >> 6, ch = i & 63;
        xcl[(pos0 + p) * C_ + ch] = __float2bfloat16(tile[ch][p]);
    }
}

// ---------------------------------------------------------------------------
// BARRIER-FREE per-wave streaming MFMA 3x3x3 conv (conv1) — R10 verbatim.
// ---------------------------------------------------------------------------
__global__ __launch_bounds__(256) void conv_stream_kernel(
    const __hip_bfloat16* __restrict__ in_cl,
    const __hip_bfloat16* __restrict__ wTs,
    const float* __restrict__ bias,
    __hip_bfloat16* __restrict__ out_cl_b16) {
    __shared__ __hip_bfloat16 ts[32 * 72];

    const int tid = threadIdx.x;
    const int wv = tid >> 6;
    const int lane = tid & 63;
    const int l15 = lane & 15;
    const int quad = lane >> 4;
    DECODE_SWZ_CONV(blockIdx.x, t, h, wh)
    const int w0 = wh * 32;
    const int pg = wv >> 1;
    const int chf = wv & 1;
    const int wpos = w0 + pg * 16 + l15;
    const int posbase = t * HW_ + h * W_;

    floatx4 acc0 = (floatx4){0.f, 0.f, 0.f, 0.f};
    floatx4 acc1 = (floatx4){0.f, 0.f, 0.f, 0.f};
    const bf16x8 z = {};
    const __hip_bfloat16* wb = wTs + chf * 2048 + lane * 8;

    const int ktlo = (t == 0) ? 1 : 0;
    const int kthi = (t == T_ - 1) ? 2 : 3;

    for (int kt = ktlo; kt < kthi; ++kt) {
        const int t_in = t - 1 + kt;
#pragma unroll 1
        for (int kh = 0; kh < 3; ++kh) {
            const int h_in = h - 1 + kh;
            if ((unsigned)h_in >= H_) continue;
            const int rowbase = t_in * HW_ + h_in * W_;
#pragma unroll
            for (int kw = 0; kw < 3; ++kw) {
                const int tap = kt * 9 + kh * 3 + kw;
                const int w_in = wpos - 1 + kw;
                const bool v = (unsigned)w_in < W_;
                const int wc = v ? w_in : 0;
                const __hip_bfloat16* ap = in_cl + (rowbase + wc) * C_ + quad * 8;
                bf16x8 a0 = *(const bf16x8*)(ap);
                bf16x8 a1 = *(const bf16x8*)(ap + 32);
                a0 = v ? a0 : z;
                a1 = v ? a1 : z;
                const __hip_bfloat16* bp = wb + tap * 4096;
                const bf16x8 b00 = *(const bf16x8*)(bp);
                const bf16x8 b01 = *(const bf16x8*)(bp + 512);
                const bf16x8 b10 = *(const bf16x8*)(bp + 1024);
                const bf16x8 b11 = *(const bf16x8*)(bp + 1536);
                acc0 = __builtin_amdgcn_mfma_f32_16x16x32_bf16(a0, b00, acc0, 0, 0, 0);
                acc0 = __builtin_amdgcn_mfma_f32_16x16x32_bf16(a1, b01, acc0, 0, 0, 0);
                acc1 = __builtin_amdgcn_mfma_f32_16x16x32_bf16(a0, b10, acc1, 0, 0, 0);
                acc1 = __builtin_amdgcn_mfma_f32_16x16x32_bf16(a1, b11, acc1, 0, 0, 0);
            }
        }
    }

    const int n0 = chf * 32 + l15;
    const float bv0 = bias[n0], bv1 = bias[n0 + 16];
#pragma unroll
    for (int r = 0; r < 4; ++r) {
        const int p = pg * 16 + quad * 4 + r;
        float v0 = acc0[r] + bv0;
        v0 = (v0 >= 0.f) ? v0 : 0.01f * v0;
        float v1 = acc1[r] + bv1;
        v1 = (v1 >= 0.f) ? v1 : 0.01f * v1;
        ts[p * 72 + n0] = __float2bfloat16(v0);
        ts[p * 72 + n0 + 16] = __float2bfloat16(v1);
    }
    __syncthreads();
    {
        const int p = tid >> 3, ck = tid & 7;
        const uint4 v4 = *(const uint4*)&ts[p * 72 + ck * 8];
        *(uint4*)&out_cl_b16[(posbase + w0 + p) * C_ + ck * 8] = v4;
    }
}

// ---------------------------------------------------------------------------
// FUSED offsets-conv + deform + residual (R27): R11's wave-autonomous
// structure + LDS-WINDOW gathers. Diagnosis: the invariant 92us across
// R0/R3/R10/R11 with +46% at 2x requests (R5) = scattered-VMEM service
// wall (~0.46 lane-req/cyc/CU). Fix: per kt-plane, stage rows h-2..h+3 x
// ALL 64 cols x 64ch (48KB) into LDS coalesced, then gather via
// ds_read_b128 (>=4 lanes/cyc). XOR chunk-swizzle (chunk ^= rw&7) makes
// gather reads ~2-way (free); without it they'd be 16-way. Window uses
// RAW-coord rows (clamped source rows), reproducing R0 clamp+mask
// semantics exactly; rare |dh|>=2 lanes take the R11 global fallback.
// Barriers: 2 per kt-group (6 total), none per-tap.
// ---------------------------------------------------------------------------
struct G2 {
    bf16x8 a[4];          // 4 corners, channels quad*8 .. +7
    bf16x8 b[4];          // 4 corners, channels 32+quad*8 .. +7
    float w00, w01, w10, w11;
};

__global__ __launch_bounds__(256) void deform_fused_kernel(
    const __hip_bfloat16* __restrict__ y1b,
    const __hip_bfloat16* __restrict__ woffs, const float* __restrict__ boff,
    const __hip_bfloat16* __restrict__ wds, const float* __restrict__ bd,
    const __hip_bfloat16* __restrict__ xclb, const __hip_bfloat16* __restrict__ wrs,
    const float* __restrict__ br, float* __restrict__ out) {
    __shared__ __hip_bfloat16 win[6 * 64 * 64];   // 49152 B, chunk-swizzled
    __shared__ float offs[4][16][OSTR2];          // 14848 B, wave-private
    // total 64000 B <= 64KB

    const int tid = threadIdx.x;
    const int wv = tid >> 6;
    const int lane = tid & 63;
    const int l15 = lane & 15;
    const int quad = lane >> 4;
    DECODE_SWZ_ROW(blockIdx.x, t, h)
    const int posbase = t * HW_ + h * W_;
    const int pw = wv * 16 + l15;            // this lane's position (w coord)

    const int ktlo = (t == 0) ? 1 : 0;
    const int kthi = (t == T_ - 1) ? 2 : 3;

    // ========== Phase 1: per-wave offsets conv (no barrier; R11 verbatim) ==
    {
        floatx4 oacc[4];
#pragma unroll
        for (int g = 0; g < 4; ++g) oacc[g] = (floatx4){0.f, 0.f, 0.f, 0.f};
        const bf16x8 z = {};

        for (int kt = ktlo; kt < kthi; ++kt) {
            const int t_in = t - 1 + kt;
#pragma unroll 1
            for (int kh = 0; kh < 3; ++kh) {
                const int h_in = h - 1 + kh;
                if ((unsigned)h_in >= H_) continue;
                const int rowbase = t_in * HW_ + h_in * W_;
#pragma unroll
                for (int kw = 0; kw < 3; ++kw) {
                    const int tap = kt * 9 + kh * 3 + kw;
                    const int w_in = pw - 1 + kw;
                    const bool v = (unsigned)w_in < W_;
                    const int wc = v ? w_in : 0;
                    const __hip_bfloat16* ap = y1b + (rowbase + wc) * C_ + quad * 8;
                    bf16x8 a0 = *(const bf16x8*)(ap);
                    bf16x8 a1 = *(const bf16x8*)(ap + 32);
                    a0 = v ? a0 : z;
                    a1 = v ? a1 : z;
                    const __hip_bfloat16* op = woffs + tap * 4096 + lane * 8;
#pragma unroll
                    for (int g = 0; g < 4; ++g) {
                        const bf16x8 b0 = *(const bf16x8*)(op + g * 1024);
                        const bf16x8 b1 = *(const bf16x8*)(op + g * 1024 + 512);
                        oacc[g] = __builtin_amdgcn_mfma_f32_16x16x32_bf16(a0, b0, oacc[g], 0, 0, 0);
                        oacc[g] = __builtin_amdgcn_mfma_f32_16x16x32_bf16(a1, b1, oacc[g], 0, 0, 0);
                    }
                }
            }
        }
#pragma unroll
        for (int g = 0; g < 4; ++g) {
            const int idx = g * 16 + l15;
            if (idx < NOFF) {
                const float bo = boff[idx];
#pragma unroll
                for (int r = 0; r < 4; ++r)
                    offs[wv][quad * 4 + r][idx] = oacc[g][r] + bo;
            }
        }
    }
    asm volatile("s_waitcnt lgkmcnt(0)" ::: "memory");  // same-wave publish

    // ========== Phase 2: window-gather deform + residual ==========
    floatx4 acc[4], racc[4];
#pragma unroll
    for (int g = 0; g < 4; ++g) {
        acc[g] = (floatx4){0.f, 0.f, 0.f, 0.f};
        racc[g] = (floatx4){0.f, 0.f, 0.f, 0.f};
    }

    // residual 1x1 conv (R11 verbatim)
    {
        const __hip_bfloat16* ap = xclb + (posbase + pw) * C_ + quad * 8;
        const bf16x8 ra0 = *(const bf16x8*)(ap);
        const bf16x8 ra1 = *(const bf16x8*)(ap + 32);
        const __hip_bfloat16* q = wrs + lane * 8;
#pragma unroll
        for (int g = 0; g < 4; ++g) {
            const bf16x8 r0 = *(const bf16x8*)(q + g * 1024);
            const bf16x8 r1 = *(const bf16x8*)(q + g * 1024 + 512);
            racc[g] = __builtin_amdgcn_mfma_f32_16x16x32_bf16(ra0, r0, racc[g], 0, 0, 0);
            racc[g] = __builtin_amdgcn_mfma_f32_16x16x32_bf16(ra1, r1, racc[g], 0, 0, 0);
        }
    }

    auto load_off = [&](int k, float& dh, float& dw) {
        dh = offs[wv][l15][2 * k];
        dw = offs[wv][l15][2 * k + 1];
    };
    // window read: row rr (0..5), col cc (0..63), 16B chunk (0..7), swizzled
    auto rdwin = [&](int rr, int cc, int chunk) -> bf16x8 {
        const int u = (rr * 64 + cc) * 8 + (chunk ^ (cc & 7));
        return *(const bf16x8*)((const char*)win + u * 16);
    };
    auto gatherW = [&](int k, float dh, float dw, G2& g) {
        const int kh = (k / 3) % 3, kw = k % 3;
        const float hs = (float)(h - 1 + kh) + dh;
        const float wsv = (float)(pw - 1 + kw) + dw;
        const float h0f = floorf(hs), w0f = floorf(wsv);
        const float fh = hs - h0f, fw = wsv - w0f;
        const int h0i = (int)h0f, w0i = (int)w0f;
        const int h1i = h0i + 1, w1i = w0i + 1;
        const float m_h0 = ((unsigned)h0i < H_) ? 1.f : 0.f;
        const float m_h1 = ((unsigned)h1i < H_) ? 1.f : 0.f;
        const float m_w0 = ((unsigned)w0i < W_) ? 1.f : 0.f;
        const float m_w1 = ((unsigned)w1i < W_) ? 1.f : 0.f;
        g.w00 = (1.f - fh) * (1.f - fw) * m_h0 * m_w0;
        g.w01 = (1.f - fh) * fw * m_h0 * m_w1;
        g.w10 = fh * (1.f - fw) * m_h1 * m_w0;
        g.w11 = fh * fw * m_h1 * m_w1;
        const int w0c = min(max(w0i, 0), W_ - 1);
        const int w1c = min(max(w1i, 0), W_ - 1);
        const int rh = h0i - (h - 2);
        if ((unsigned)rh <= 4u) {               // window path (h1 row = rh+1 <= 5)
            g.a[0] = rdwin(rh, w0c, quad);      g.b[0] = rdwin(rh, w0c, quad + 4);
            g.a[1] = rdwin(rh, w1c, quad);      g.b[1] = rdwin(rh, w1c, quad + 4);
            g.a[2] = rdwin(rh + 1, w0c, quad);  g.b[2] = rdwin(rh + 1, w0c, quad + 4);
            g.a[3] = rdwin(rh + 1, w1c, quad);  g.b[3] = rdwin(rh + 1, w1c, quad + 4);
        } else {                                 // rare fallback: R11 global path
            const int h0c = min(max(h0i, 0), H_ - 1);
            const int h1c = min(max(h1i, 0), H_ - 1);
            const int tb = (t - 1 + k / 9) * HW_;
            const __hip_bfloat16* p00 = y1b + (tb + h0c * W_ + w0c) * C_ + quad * 8;
            const __hip_bfloat16* p01 = y1b + (tb + h0c * W_ + w1c) * C_ + quad * 8;
            const __hip_bfloat16* p10 = y1b + (tb + h1c * W_ + w0c) * C_ + quad * 8;
            const __hip_bfloat16* p11 = y1b + (tb + h1c * W_ + w1c) * C_ + quad * 8;
            g.a[0] = *(const bf16x8*)(p00);  g.b[0] = *(const bf16x8*)(p00 + 32);
            g.a[1] = *(const bf16x8*)(p01);  g.b[1] = *(const bf16x8*)(p01 + 32);
            g.a[2] = *(const bf16x8*)(p10);  g.b[2] = *(const bf16x8*)(p10 + 32);
            g.a[3] = *(const bf16x8*)(p11);  g.b[3] = *(const bf16x8*)(p11 + 32);
        }
    };
    auto blend2 = [&](const G2& g, bf16x8& lo, bf16x8& hi) {
        union U { bf16x8 v; __hip_bfloat16 e[8]; };
        U c0, c1, c2, c3, r;
        c0.v = g.a[0]; c1.v = g.a[1]; c2.v = g.a[2]; c3.v = g.a[3];
#pragma unroll
        for (int j = 0; j < 8; ++j) {
            float f = g.w00 * __bfloat162float(c0.e[j]) + g.w01 * __bfloat162float(c1.e[j]) +
                      g.w10 * __bfloat162float(c2.e[j]) + g.w11 * __bfloat162float(c3.e[j]);
            r.e[j] = __float2bfloat16(f);
        }
        lo = r.v;
        c0.v = g.b[0]; c1.v = g.b[1]; c2.v = g.b[2]; c3.v = g.b[3];
#pragma unroll
        for (int j = 0; j < 8; ++j) {
            float f = g.w00 * __bfloat162float(c0.e[j]) + g.w01 * __bfloat162float(c1.e[j]) +
                      g.w10 * __bfloat162float(c2.e[j]) + g.w11 * __bfloat162float(c3.e[j]);
            r.e[j] = __float2bfloat16(f);
        }
        hi = r.v;
    };
    auto tapMFMA = [&](int k, const bf16x8& lo, const bf16x8& hi) {
        const __hip_bfloat16* q = wds + k * 4096 + lane * 8;
#pragma unroll
        for (int g = 0; g < 4; ++g) {
            const bf16x8 b0 = *(const bf16x8*)(q + g * 1024);
            const bf16x8 b1 = *(const bf16x8*)(q + g * 1024 + 512);
            acc[g] = __builtin_amdgcn_mfma_f32_16x16x32_bf16(lo, b0, acc[g], 0, 0, 0);
            acc[g] = __builtin_amdgcn_mfma_f32_16x16x32_bf16(hi, b1, acc[g], 0, 0, 0);
        }
    };

    G2 gA, gB;
#pragma unroll 1
    for (int kt = ktlo; kt < kthi; ++kt) {
        const int tin = t - 1 + kt;
        const int kg = kt * 9;

        LGKM_BARRIER();                 // prev group's window reads complete
        // stage window: rows h-2..h+3 (clamped src), ALL 64 cols, swizzled
        for (int i = tid; i < 6 * 64 * 8; i += 256) {
            const int rh = i >> 9;
            const int rem = i & 511;
            const int rw = rem >> 3;
            const int cc = rem & 7;
            const int hsrc = min(max(h - 2 + rh, 0), H_ - 1);
            const int u = (rh * 64 + rw) * 8 + (cc ^ (rw & 7));
            *(bf16x8*)((char*)win + u * 16) =
                *(const bf16x8*)&y1b[(tin * HW_ + hsrc * W_ + rw) * C_ + cc * 8];
        }
        LGKM_BARRIER();                 // window published

        // 9 taps, 2-slot pipeline within the group
        {
            float dh, dw;
            load_off(kg, dh, dw);
            gatherW(kg, dh, dw, gA);
        }
        int k = kg;
        for (; k + 1 < kg + 9; k += 2) {
            {
                float dh, dw;
                load_off(k + 1, dh, dw);
                gatherW(k + 1, dh, dw, gB);
                bf16x8 lo, hi;
                blend2(gA, lo, hi);
                tapMFMA(k, lo, hi);
            }
            {
                if (k + 2 < kg + 9) {
                    float dh, dw;
                    load_off(k + 2, dh, dw);
                    gatherW(k + 2, dh, dw, gA);
                }
                bf16x8 lo, hi;
                blend2(gB, lo, hi);
                tapMFMA(k + 1, lo, hi);
            }
        }
        {   // 9th tap (odd) — gA valid
            bf16x8 lo, hi;
            blend2(gA, lo, hi);
            tapMFMA(k, lo, hi);
        }
    }

    // epilogue (R11 verbatim)
#pragma unroll
    for (int g = 0; g < 4; ++g) {
        const int n = g * 16 + l15;
        const float bdv = bd[n], brv = br[n];
        floatx4 o;
#pragma unroll
        for (int r = 0; r < 4; ++r) {
            float v = acc[g][r] + bdv;
            v = (v >= 0.f) ? v : 0.01f * v;
            o[r] = v + racc[g][r] + brv;
        }
        *(floatx4*)&out[n * THW_ + posbase + wv * 16 + quad * 4] = o;
    }
}

// ---------------------------------------------------------------------------
extern "C" void kernel_launch(void* const* d_in, const int* in_sizes, int n_in,
                              void* d_out, int out_size, void* d_ws, size_t ws_size,
                              hipStream_t stream) {
    const float* x    = (const float*)d_in[0];
    const float* W1   = (const float*)d_in[1];
    const float* b1   = (const float*)d_in[2];
    const float* Woff = (const float*)d_in[3];
    const float* boff = (const float*)d_in[4];
    const float* Wd   = (const float*)d_in[5];
    const float* bd   = (const float*)d_in[6];
    const float* Wr   = (const float*)d_in[7];
    const float* br   = (const float*)d_in[8];
    float* out = (float*)d_out;

    float* ws = (float*)d_ws;
    __hip_bfloat16* xclb  = (__hip_bfloat16*)(ws);             // 2,097,152 bf16
    __hip_bfloat16* y1b   = (__hip_bfloat16*)(ws + 1048576);   // 2,097,152 bf16
    __hip_bfloat16* w1s   = (__hip_bfloat16*)(ws + 2097152);   //   110,592 bf16
    __hip_bfloat16* woffs = (__hip_bfloat16*)(ws + 2152448);   //   110,592 bf16
    __hip_bfloat16* wdsb  = (__hip_bfloat16*)(ws + 2207744);   //   110,592 bf16
    __hip_bfloat16* wrsb  = (__hip_bfloat16*)(ws + 2263040);   //     4,096 bf16
    // total ~9.1 MB

    prep_tocl_kernel<<<THW_ / 64, 256, 0, stream>>>(
        x, xclb, W1, Woff, Wd, Wr, w1s, woffs, wdsb, wrsb);

    conv_stream_kernel<<<dim3(T_ * H_ * 2), 256, 0, stream>>>(
        xclb, w1s, b1, y1b);

    deform_fused_kernel<<<dim3(T_ * H_), 256, 0, stream>>>(
        y1b, woffs, boff, wdsb, bd, xclb, wrsb, br, out);
}